// Round 7
// baseline (296.729 us; speedup 1.0000x reference)
//
#include <hip/hip_runtime.h>
#include <hip/hip_bf16.h>

#define DIMN 1024
#define NHEAD 8
#define ESPL 128
#define NB 4
#define SEQ 2048
#define NROWS (NB * SEQ)
#define LNEPS 1e-6f
#define L2E 1.442695041f

typedef unsigned short u16;
typedef unsigned int u32;
typedef __attribute__((ext_vector_type(8))) short short8;
typedef __attribute__((ext_vector_type(4))) short s16x4;
typedef __attribute__((ext_vector_type(4))) float f32x4;

__device__ __forceinline__ u16 f2bf(float f) {
  u32 u = __float_as_uint(f);
  u += 0x7FFFu + ((u >> 16) & 1u);  // round-to-nearest-even
  return (u16)(u >> 16);
}

// single-instruction pack of 2 f32 -> 2 bf16 (RNE), T12 (learn_hip m214v22)
__device__ __forceinline__ u32 pk2bf(float a, float b) {
  u32 r;
  asm("v_cvt_pk_bf16_f32 %0, %1, %2" : "=v"(r) : "v"(a), "v"(b));
  return r;
}

__device__ __forceinline__ uint2 pack4bf(float4 v) {
  uint2 r;
  r.x = pk2bf(v.x, v.y);
  r.y = pk2bf(v.z, v.w);
  return r;
}

// native 2^x (v_exp_f32); gfx9 VALU deps are HW-interlocked so inline asm is safe
__device__ __forceinline__ float fexp2(float x) {
  float r;
  asm("v_exp_f32 %0, %1" : "=v"(r) : "v"(x));
  return r;
}

__device__ __forceinline__ float eluf(float x) { return x > 0.f ? x : expm1f(x); }

// async global->LDS DMA, 16 B per lane; lds dest = wave-uniform base + lane*16
__device__ __forceinline__ void gl2lds16(const u16* g, u16* l) {
  __builtin_amdgcn_global_load_lds((const __attribute__((address_space(1))) u32*)g,
                                   (__attribute__((address_space(3))) u32*)l, 16, 0, 0);
}

// ------- LN apply: modb = bf16(LN(mod)) using precomputed row sums -------
__global__ __launch_bounds__(256) void ln_apply(const float* __restrict__ modp,
                                                const float* __restrict__ gamma,
                                                const float* __restrict__ beta,
                                                const float* __restrict__ s1p,
                                                const float* __restrict__ s2p,
                                                u16* __restrict__ outb) {
  int base = (blockIdx.x * 256 + threadIdx.x) * 4;
  int row = base >> 10, col = base & 1023;
  float s1 = s1p[row], s2 = s2p[row];
  float mu = s1 * (1.f / DIMN);
  float rsd = rsqrtf(fmaxf(s2 * (1.f / DIMN) - mu * mu, 0.f) + LNEPS);
  float4 v = *(const float4*)(modp + base);
  float4 g = *(const float4*)(gamma + col);
  float4 bb = *(const float4*)(beta + col);
  v.x = (v.x - mu) * rsd * g.x + bb.x;
  v.y = (v.y - mu) * rsd * g.y + bb.y;
  v.z = (v.z - mu) * rsd * g.z + bb.z;
  v.w = (v.w - mu) * rsd * g.w + bb.w;
  *(uint2*)(outb + base) = pack4bf(v);
}

// ------- weight transpose + fp32->bf16: dst[n*K+k] = bf16(src[k*N+n]) -------
__device__ __forceinline__ void wtrans_body(u16 (*tl)[68], const float* __restrict__ src,
                                            u16* __restrict__ dst, int K, int N, int n0,
                                            int k0) {
  const int t = threadIdx.x;
  const int r = t >> 2;
#pragma unroll
  for (int j = 0; j < 4; j++) {
    int f = (t & 3) + j * 4;
    float4 v = *(const float4*)(src + (size_t)(k0 + r) * N + n0 + f * 4);
    *(uint2*)&tl[r][f * 4] = pack4bf(v);
  }
  __syncthreads();
#pragma unroll
  for (int j = 0; j < 4; j++) {
    int f = (t & 3) + j * 4;
    ushort4 o;
    o.x = tl[f * 4 + 0][r];
    o.y = tl[f * 4 + 1][r];
    o.z = tl[f * 4 + 2][r];
    o.w = tl[f * 4 + 3][r];
    *(ushort4*)(dst + (size_t)(n0 + r) * K + k0 + f * 4) = o;
  }
}

// ------- fused prep: x->bf16 convert + all weight transposes in ONE launch -----
// blocks [0,8192): conv; [8192,8704): W_in/Wf 64x64 transpose tiles;
// [8704,8800): per-head Wq/Wk/Wv transpose tiles. Branch is block-uniform.
__global__ __launch_bounds__(256) void prep_fused(
    const float* __restrict__ x, u16* __restrict__ xb, const float* __restrict__ W_in,
    u16* __restrict__ wt1, const float* __restrict__ Wf, u16* __restrict__ wt2,
    const float* __restrict__ Wq, const float* __restrict__ Wk, const float* __restrict__ Wv,
    u16* __restrict__ dq, u16* __restrict__ dk, u16* __restrict__ dv) {
  __shared__ u16 tl[64][68];
  const int bid = blockIdx.x;
  if (bid < NROWS) {
    int base = (bid * 256 + threadIdx.x) * 4;
    *(uint2*)(xb + base) = pack4bf(*(const float4*)(x + base));
  } else if (bid < NROWS + 512) {
    int z = bid - NROWS;
    const float* s = (z & 256) ? Wf : W_in;
    u16* d = (z & 256) ? wt2 : wt1;
    z &= 255;
    wtrans_body(tl, s, d, DIMN, DIMN, (z & 15) * 64, (z >> 4) * 64);
  } else {
    int z = bid - NROWS - 512;  // 0..95
    int xy = z & 3, zz = z >> 2;
    int mi = zz >> 3, hh = zz & 7;
    const float* s = (mi == 0) ? Wq : (mi == 1) ? Wk : Wv;
    u16* d = (mi == 0) ? dq : (mi == 1) ? dk : dv;
    s += (size_t)hh * ESPL * ESPL;
    d += (size_t)hh * ESPL * ESPL;
    wtrans_body(tl, s, d, ESPL, ESPL, (xy & 1) * 64, (xy >> 1) * 64);
  }
}

// ------- pure-bf16 MFMA GEMM: async-DMA double-buffered, 128x128 tile, BK=64 -------
// Operand-swapped MFMA (bfr first): acc[mt][nt][r] = C[m=..+l16][n=..+quad*4+r]
// -> per-lane 4 consecutive cols -> float4 stores / float4 resid+bias loads.
// T1 XCD swizzle: each XCD gets 8 contiguous m-panels x all 8 n-tiles.
template <int MODE>
__global__ __launch_bounds__(256, 2) void gemm_bf16(
    const u16* __restrict__ A, const u16* __restrict__ Bt, const float* __restrict__ resid,
    const float* __restrict__ bias, float* __restrict__ s1p, float* __restrict__ s2p,
    float* __restrict__ C) {
  __shared__ __align__(16) char lds[65536];  // [As0|Bs0|As1|Bs1] 16 KB each
  const int t = threadIdx.x;
  const int w = t >> 6, lane = t & 63, quad = lane >> 4, l16 = lane & 15;
  const int wm = w & 1, wn = w >> 1;
  const int lin = blockIdx.x + gridDim.x * blockIdx.y;  // 0..511
  const int xcd = lin & 7, slot = lin >> 3;             // 64 slots per XCD
  const int m0 = (xcd * 8 + (slot >> 3)) * 128;
  const int n0 = (slot & 7) * 128;

  auto stage = [&](int koff, int bi) {
    const u16* ag = A + (size_t)m0 * DIMN + koff;
    const u16* bg = Bt + (size_t)n0 * DIMN + koff;
    u16* As = (u16*)(lds + bi * 32768);
    u16* Bs = (u16*)(lds + bi * 32768 + 16384);
#pragma unroll
    for (int i = 0; i < 4; i++) {
      int pbase = (w * 4 + i) * 64;
      int p = pbase + lane;
      int r = p >> 3, c8 = (p & 7) ^ (r & 7);
      gl2lds16(ag + (size_t)r * DIMN + c8 * 8, As + pbase * 8);
      gl2lds16(bg + (size_t)r * DIMN + c8 * 8, Bs + pbase * 8);
    }
  };

  f32x4 acc[4][4];
#pragma unroll
  for (int mt = 0; mt < 4; mt++)
#pragma unroll
    for (int nt = 0; nt < 4; nt++) acc[mt][nt] = (f32x4){0.f, 0.f, 0.f, 0.f};

  stage(0, 0);
  __syncthreads();
  for (int kt = 0; kt < DIMN / 64; kt++) {
    if (kt + 1 < DIMN / 64) stage((kt + 1) * 64, (kt + 1) & 1);
    const u16* As = (const u16*)(lds + (kt & 1) * 32768);
    const u16* Bs = (const u16*)(lds + (kt & 1) * 32768 + 16384);
#pragma unroll
    for (int ks = 0; ks < 2; ks++) {
      short8 af[4], bfr[4];
#pragma unroll
      for (int mt = 0; mt < 4; mt++) {
        int row = wm * 64 + mt * 16 + l16;
        int pc = (ks * 4 + quad) ^ (row & 7);
        af[mt] = *(const short8*)(As + row * 64 + pc * 8);
      }
#pragma unroll
      for (int nt = 0; nt < 4; nt++) {
        int row = wn * 64 + nt * 16 + l16;
        int pc = (ks * 4 + quad) ^ (row & 7);
        bfr[nt] = *(const short8*)(Bs + row * 64 + pc * 8);
      }
#pragma unroll
      for (int mt = 0; mt < 4; mt++)
#pragma unroll
        for (int nt = 0; nt < 4; nt++)
          acc[mt][nt] = __builtin_amdgcn_mfma_f32_16x16x32_bf16(bfr[nt], af[mt], acc[mt][nt], 0, 0, 0);
    }
    __syncthreads();
  }
  // epilogue: row m = ..+l16 (quad-invariant); cols n = ..+quad*4+r
#pragma unroll
  for (int mt = 0; mt < 4; mt++) {
    int row = m0 + wm * 64 + mt * 16 + l16;
    float s1 = 0.f, s2 = 0.f;
#pragma unroll
    for (int nt = 0; nt < 4; nt++) {
      int col = n0 + wn * 64 + nt * 16 + quad * 4;
      size_t off = (size_t)row * DIMN + col;
      f32x4 v = acc[mt][nt];
      if (MODE == 0) {
        *(f32x4*)(C + off) = v;
        s1 += (v[0] + v[1]) + (v[2] + v[3]);
        s2 += (v[0] * v[0] + v[1] * v[1]) + (v[2] * v[2] + v[3] * v[3]);
      } else {
        float4 rv = *(const float4*)(resid + off);
        float4 bv = *(const float4*)(bias + col);
        float4 o;
        o.x = rv.x + eluf(v[0] + bv.x);
        o.y = rv.y + eluf(v[1] + bv.y);
        o.z = rv.z + eluf(v[2] + bv.z);
        o.w = rv.w + eluf(v[3] + bv.w);
        *(float4*)(C + off) = o;
      }
    }
    if (MODE == 0) {
      s1 += __shfl_xor(s1, 16);
      s1 += __shfl_xor(s1, 32);
      s2 += __shfl_xor(s2, 16);
      s2 += __shfl_xor(s2, 32);
      if (quad == 0) {
        atomicAdd(s1p + row, s1);
        atomicAdd(s2p + row, s2);
      }
    }
  }
}

// ------- QKV: per (b,h), 128 s-rows x 128 e, K=128; LN1 fused in A-staging -------
// T1 XCD swizzle: XCD k handles head hh=k only -> its 96 KB of Wq/Wk/Wv stay in L2.
// Q/K use operand-swapped MFMA for uint2 stores; V keeps original order.
#define QP 136

__global__ __launch_bounds__(256) void qkv_mfma(
    const float* __restrict__ modp, const u16* __restrict__ wqt, const u16* __restrict__ wkt,
    const u16* __restrict__ wvt, const float* __restrict__ gamma, const float* __restrict__ beta,
    const float* __restrict__ s1p, const float* __restrict__ s2p, u16* __restrict__ qo,
    u16* __restrict__ ko, u16* __restrict__ vto) {
  __shared__ u16 Asl[128 * QP];
  __shared__ u16 Bsl[128 * QP];
  const int t = threadIdx.x;
  const int w = t >> 6, lane = t & 63, quad = lane >> 4, l16 = lane & 15;
  const int wm = w & 1, wn = w >> 1;
  const int lin = blockIdx.x + gridDim.x * blockIdx.y;  // 0..511
  const int xcd = lin & 7, slot = lin >> 3;
  const int s0 = (slot >> 2) * 128;
  const int bh = (slot & 3) * 8 + xcd;  // hh == xcd
  const int b = bh >> 3, hh = bh & 7;
  const int sr8 = t >> 3, sf8 = t & 7;
#pragma unroll
  for (int p = 0; p < 4; p++) {
    int r = sr8 + 32 * p;
    int rowg = b * SEQ + s0 + r;
    float s1 = s1p[rowg], s2 = s2p[rowg];
    float mu = s1 * (1.f / DIMN);
    float rsd = rsqrtf(fmaxf(s2 * (1.f / DIMN) - mu * mu, 0.f) + LNEPS);
    const float* ap = modp + (size_t)rowg * DIMN + hh * ESPL;
#pragma unroll
    for (int j = 0; j < 4; j++) {
      int f = sf8 + j * 8;
      float4 v = *(const float4*)(ap + f * 4);
      float4 g = *(const float4*)(gamma + hh * ESPL + f * 4);
      float4 bb = *(const float4*)(beta + hh * ESPL + f * 4);
      v.x = (v.x - mu) * rsd * g.x + bb.x;
      v.y = (v.y - mu) * rsd * g.y + bb.y;
      v.z = (v.z - mu) * rsd * g.z + bb.z;
      v.w = (v.w - mu) * rsd * g.w + bb.w;
      *(uint2*)(Asl + r * QP + f * 4) = pack4bf(v);
    }
  }
  __syncthreads();
  short8 afr[4][4];
#pragma unroll
  for (int k4 = 0; k4 < 4; k4++)
#pragma unroll
    for (int mt = 0; mt < 4; mt++)
      afr[k4][mt] = *(const short8*)(Asl + (wm * 64 + mt * 16 + l16) * QP + k4 * 32 + quad * 8);

  const u16* Ws[3] = {wqt, wkt, wvt};
  for (int mi = 0; mi < 3; mi++) {
    __syncthreads();
    const u16* wsrc = Ws[mi] + ((size_t)hh << 14);
#pragma unroll
    for (int p = 0; p < 4; p++) {
      int r = sr8 + 32 * p;
#pragma unroll
      for (int j = 0; j < 2; j++) {
        int f = sf8 + j * 8;
        *(uint4*)(Bsl + r * QP + f * 8) = *(const uint4*)(wsrc + r * ESPL + f * 8);
      }
    }
    __syncthreads();
    f32x4 acc[4][4];
#pragma unroll
    for (int mt = 0; mt < 4; mt++)
#pragma unroll
      for (int nt = 0; nt < 4; nt++) acc[mt][nt] = (f32x4){0.f, 0.f, 0.f, 0.f};
#pragma unroll
    for (int k4 = 0; k4 < 4; k4++) {
      short8 bfr[4];
#pragma unroll
      for (int nt = 0; nt < 4; nt++)
        bfr[nt] = *(const short8*)(Bsl + (wn * 64 + nt * 16 + l16) * QP + k4 * 32 + quad * 8);
      if (mi < 2) {
#pragma unroll
        for (int mt = 0; mt < 4; mt++)
#pragma unroll
          for (int nt = 0; nt < 4; nt++)
            acc[mt][nt] = __builtin_amdgcn_mfma_f32_16x16x32_bf16(bfr[nt], afr[k4][mt], acc[mt][nt], 0, 0, 0);
      } else {
#pragma unroll
        for (int mt = 0; mt < 4; mt++)
#pragma unroll
          for (int nt = 0; nt < 4; nt++)
            acc[mt][nt] = __builtin_amdgcn_mfma_f32_16x16x32_bf16(afr[k4][mt], bfr[nt], acc[mt][nt], 0, 0, 0);
      }
    }
    if (mi < 2) {
      u16* o = (mi == 0) ? qo : ko;
#pragma unroll
      for (int mt = 0; mt < 4; mt++) {
        int s = s0 + wm * 64 + mt * 16 + l16;
#pragma unroll
        for (int nt = 0; nt < 4; nt++) {
          int e0 = wn * 64 + nt * 16 + quad * 4;
          uint2 pk;
          pk.x = pk2bf(acc[mt][nt][0], acc[mt][nt][1]);
          pk.y = pk2bf(acc[mt][nt][2], acc[mt][nt][3]);
          *(uint2*)(o + ((size_t)bh * SEQ + s) * ESPL + e0) = pk;
        }
      }
    } else {
#pragma unroll
      for (int mt = 0; mt < 4; mt++)
#pragma unroll
        for (int nt = 0; nt < 4; nt++) {
          int e = wn * 64 + nt * 16 + l16;
          int sbase = s0 + wm * 64 + mt * 16 + quad * 4;
          uint2 pk;
          pk.x = pk2bf(acc[mt][nt][0], acc[mt][nt][1]);
          pk.y = pk2bf(acc[mt][nt][2], acc[mt][nt][3]);
          *(uint2*)(vto + ((size_t)bh * ESPL + e) * SEQ + sbase) = pk;
        }
    }
  }
}

// ------- MFMA flash attention v10: v9 + softmax on native exp2 pipe -------
// P = 2^(S*log2e - mk*log2e) via v_fma + v_exp_f32 (2 ops vs 3 for __expf(S-mk))
#define OBP 132  // epilogue Obuf pitch (f32)
#define RESCALE_THR 8.f

__global__ __launch_bounds__(256, 2) void attn_mfma(const u16* __restrict__ q,
                                                    const u16* __restrict__ kk,
                                                    const u16* __restrict__ vt,
                                                    float* __restrict__ modp,
                                                    float* __restrict__ s1p,
                                                    float* __restrict__ s2p) {
  // [Ks0|Vs0|Ks1|Vs1] 16 KB each + 16 KB P^T scratch (4 KB/wave) = 80 KB (2 blk/CU)
  __shared__ __align__(16) char lds[81920];
  const int t = threadIdx.x;
  const int w = t >> 6, lane = t & 63, quad = lane >> 4, l16 = lane & 15;
  const int lin = blockIdx.x + gridDim.x * blockIdx.y;  // 0..511
  const int xcd = lin & 7, slot = lin >> 3;             // 64 slots per XCD
  const int qt = slot & 15;                             // 0..15
  const int bh = xcd * 4 + (slot >> 4);                 // 4 bh per XCD
  const int b = bh >> 3, hh = bh & 7;
  const size_t qkbase = (size_t)bh * SEQ * ESPL;
  const int qrow0 = qt * 128 + w * 32;
  const u16* kg0 = kk + qkbase;
  const u16* vg0 = vt + qkbase;
  // per-wave P^T scratch: P_t[g][q=l16][k 0..63] bf16, 16B-XOR-swizzled rows
  char* Pt = lds + 65536 + w * 4096;
  const int swz = (l16 & 7) << 4;

  short8 qf[2][4];
#pragma unroll
  for (int g = 0; g < 2; g++) {
    const u16* qrow = q + qkbase + (size_t)(qrow0 + g * 16 + l16) * ESPL + quad * 8;
#pragma unroll
    for (int kc = 0; kc < 4; kc++) qf[g][kc] = *(const short8*)(qrow + kc * 32);
  }

  float m_st[2] = {-1e30f, -1e30f}, l_st[2] = {0.f, 0.f};
  f32x4 oacc[2][8];
#pragma unroll
  for (int g = 0; g < 2; g++)
#pragma unroll
    for (int et = 0; et < 8; et++) oacc[g][et] = (f32x4){0.f, 0.f, 0.f, 0.f};

  auto stage = [&](int kt, int bi) {
    const u16* kg = kg0 + (size_t)kt * 64 * ESPL;
    const u16* vg = vg0 + (size_t)kt * 64;
    u16* Ksb = (u16*)(lds + bi * 32768);
    u16* Vsb = (u16*)(lds + bi * 32768 + 16384);
#pragma unroll
    for (int i = 0; i < 4; i++) {
      int pbase = w * 64 + i * 256;
      int p = pbase + lane;
      int r = p >> 4, c8 = (p & 15) ^ (r & 15);
      gl2lds16(kg + r * ESPL + c8 * 8, Ksb + pbase * 8);
      int e = p >> 3, v8 = (p & 7) ^ (e & 7);
      gl2lds16(vg + (size_t)e * SEQ + v8 * 8, Vsb + pbase * 8);
    }
  };

  stage(0, 0);
  __syncthreads();

  for (int kt = 0; kt < SEQ / 64; kt++) {
    if (kt + 1 < SEQ / 64) stage(kt + 1, (kt + 1) & 1);
    const u16* Ks = (const u16*)(lds + (kt & 1) * 32768);
    const u16* Vs = (const u16*)(lds + (kt & 1) * 32768 + 16384);
    f32x4 sacc[4][2];
#pragma unroll
    for (int mt = 0; mt < 4; mt++)
#pragma unroll
      for (int g = 0; g < 2; g++) sacc[mt][g] = (f32x4){0.f, 0.f, 0.f, 0.f};
    __builtin_amdgcn_s_setprio(1);
#pragma unroll
    for (int mt = 0; mt < 4; mt++) {
#pragma unroll
      for (int kc = 0; kc < 4; kc++) {
        short8 kf = *(const short8*)(Ks + (mt * 16 + l16) * 128 + (((kc * 4 + quad) ^ l16) << 3));
        sacc[mt][0] = __builtin_amdgcn_mfma_f32_16x16x32_bf16(kf, qf[0][kc], sacc[mt][0], 0, 0, 0);
        sacc[mt][1] = __builtin_amdgcn_mfma_f32_16x16x32_bf16(kf, qf[1][kc], sacc[mt][1], 0, 0, 0);
      }
    }
    __builtin_amdgcn_s_setprio(0);
    float alpha[2];
    bool updf[2];
#pragma unroll
    for (int g = 0; g < 2; g++) {
      // tree reduce over the 16 local S values (depth 3)
      const f32x4 a = sacc[0][g], b2 = sacc[1][g], c2 = sacc[2][g], d2 = sacc[3][g];
      float t0 = fmaxf(fmaxf(a[0], a[1]), a[2]);
      float t1 = fmaxf(fmaxf(a[3], b2[0]), b2[1]);
      float t2 = fmaxf(fmaxf(b2[2], b2[3]), c2[0]);
      float t3 = fmaxf(fmaxf(c2[1], c2[2]), c2[3]);
      float t4 = fmaxf(fmaxf(d2[0], d2[1]), d2[2]);
      float mloc = fmaxf(fmaxf(fmaxf(t0, t1), t2), fmaxf(fmaxf(t3, t4), d2[3]));
      mloc = fmaxf(mloc, __shfl_xor(mloc, 16));
      mloc = fmaxf(mloc, __shfl_xor(mloc, 32));
      // defer-max (T13)
      updf[g] = !__all(mloc - m_st[g] <= RESCALE_THR);
      if (updf[g]) {
        float mnew = fmaxf(m_st[g], mloc);
        alpha[g] = fexp2((m_st[g] - mnew) * L2E);
        m_st[g] = mnew;
      } else {
        alpha[g] = 1.f;
      }
      const float mkn = -m_st[g] * L2E;  // fold max-subtract into the exp2 fma
      float sum = 0.f;
#pragma unroll
      for (int mt = 0; mt < 4; mt++) {
        float p0 = fexp2(fmaf(sacc[mt][g][0], L2E, mkn));
        float p1 = fexp2(fmaf(sacc[mt][g][1], L2E, mkn));
        float p2 = fexp2(fmaf(sacc[mt][g][2], L2E, mkn));
        float p3 = fexp2(fmaf(sacc[mt][g][3], L2E, mkn));
        sum += (p0 + p1) + (p2 + p3);
        uint2 pkv = make_uint2(pk2bf(p0, p1), pk2bf(p2, p3));
        // P^T[q=l16][k = mt*16 + quad*4 + 0..3] (bf16), 16B-granular XOR swizzle
        *(uint2*)(Pt + g * 2048 + l16 * 128 + ((mt * 32 + quad * 8) ^ swz)) = pkv;
      }
      sum += __shfl_xor(sum, 16);
      sum += __shfl_xor(sum, 32);
      l_st[g] = l_st[g] * alpha[g] + sum;
    }
    if (updf[0]) {  // wave-uniform branch (from __all)
#pragma unroll
      for (int et = 0; et < 8; et++)
#pragma unroll
        for (int r = 0; r < 4; r++) oacc[0][et][r] *= alpha[0];
    }
    if (updf[1]) {
#pragma unroll
      for (int et = 0; et < 8; et++)
#pragma unroll
        for (int r = 0; r < 4; r++) oacc[1][et][r] *= alpha[1];
    }
    // B-fragments for 16x16x32 PV: lane needs P[k32=quad*8+j][q=l16], i.e. one
    // contiguous b128 from its own P^T row (same-wave write->read, lgkm-ordered)
    short8 pb[2][2];
#pragma unroll
    for (int g = 0; g < 2; g++)
#pragma unroll
      for (int mtp = 0; mtp < 2; mtp++)
        pb[g][mtp] = *(const short8*)(Pt + g * 2048 + l16 * 128 + ((mtp * 64 + quad * 16) ^ swz));
    __builtin_amdgcn_s_setprio(1);
#pragma unroll
    for (int et = 0; et < 8; et++) {
#pragma unroll
      for (int mtp = 0; mtp < 2; mtp++) {
        // V^T[e = et*16+l16][k32 = mtp*32 + quad*8 + 0..7]; Vs chunk = (mtp*4+quad)^(e&7)
        short8 vf8 = *(const short8*)(Vs + (size_t)(et * 16 + l16) * 64 +
                                      (((mtp * 4 + quad) ^ (l16 & 7)) << 3));
        oacc[0][et] = __builtin_amdgcn_mfma_f32_16x16x32_bf16(vf8, pb[0][mtp], oacc[0][et], 0, 0, 0);
        oacc[1][et] = __builtin_amdgcn_mfma_f32_16x16x32_bf16(vf8, pb[1][mtp], oacc[1][et], 0, 0, 0);
      }
    }
    __builtin_amdgcn_s_setprio(0);
    __syncthreads();  // drains DMA + all waves done reading this buffer
  }

  // single-barrier epilogue: wave w owns Obuf region w (32 x OBP f32 = 16.9 KB,
  // 4 regions = 67.6 KB <= 80 KB, all LDS dead after final loop barrier)
  float* Obuf = (float*)lds;
  {
    float linv[2] = {1.f / l_st[0], 1.f / l_st[1]};
    float* Ow = Obuf + (size_t)w * 32 * OBP;
#pragma unroll
    for (int g = 0; g < 2; g++)
#pragma unroll
      for (int et = 0; et < 8; et++) {
        f32x4 ov = oacc[g][et];
        ov[0] *= linv[g];
        ov[1] *= linv[g];
        ov[2] *= linv[g];
        ov[3] *= linv[g];
        *(f32x4*)(Ow + (size_t)(g * 16 + l16) * OBP + et * 16 + quad * 4) = ov;
      }
  }
  __syncthreads();
  const int rr = t >> 3, cc = (t & 7) << 4;
  for (int c = 0; c < 4; c++) {
    int qglob = qt * 128 + c * 32 + rr;
    float* mp = modp + ((size_t)(b * SEQ + qglob)) * DIMN + hh * ESPL + cc;
    const float* Oc = Obuf + (size_t)c * 32 * OBP + (size_t)rr * OBP + cc;
    float s1 = 0.f, s2 = 0.f;
#pragma unroll
    for (int j = 0; j < 4; j++) {
      float4 ov = *(const float4*)(Oc + j * 4);
      float4 mv = *(const float4*)(mp + j * 4);
      mv.x += ov.x;
      mv.y += ov.y;
      mv.z += ov.z;
      mv.w += ov.w;
      *(float4*)(mp + j * 4) = mv;
      s1 += (mv.x + mv.y) + (mv.z + mv.w);
      s2 += (mv.x * mv.x + mv.y * mv.y) + (mv.z * mv.z + mv.w * mv.w);
    }
    s1 += __shfl_xor(s1, 1);
    s1 += __shfl_xor(s1, 2);
    s1 += __shfl_xor(s1, 4);
    s2 += __shfl_xor(s2, 1);
    s2 += __shfl_xor(s2, 2);
    s2 += __shfl_xor(s2, 4);
    if ((t & 7) == 0) {
      atomicAdd(s1p + b * SEQ + qglob, s1);
      atomicAdd(s2p + b * SEQ + qglob, s2);
    }
  }
}

extern "C" void kernel_launch(void* const* d_in, const int* in_sizes, int n_in, void* d_out,
                              int out_size, void* d_ws, size_t ws_size, hipStream_t stream) {
  (void)in_sizes;
  (void)n_in;
  (void)out_size;
  (void)ws_size;
  const float* x = (const float*)d_in[0];
  const float* W_in = (const float*)d_in[1];
  const float* gamma = (const float*)d_in[2];
  const float* beta = (const float*)d_in[3];
  const float* Wq = (const float*)d_in[4];
  const float* Wk = (const float*)d_in[5];
  const float* Wv = (const float*)d_in[6];
  const float* Wf = (const float*)d_in[7];
  const float* bf = (const float*)d_in[8];
  float* out = (float*)d_out;

  char* ws = (char*)d_ws;
  const size_t MB = 1024ull * 1024;
  float* mod = (float*)ws;               // 32 MB fp32 [8192,1024]
  u16* qb = (u16*)(ws + 32 * MB);        // 16 MB bf16 [B,H,S,E]
  u16* kb = (u16*)(ws + 48 * MB);        // 16 MB bf16 [B,H,S,E]
  u16* vtb = (u16*)(ws + 64 * MB);       // 16 MB bf16 [B,H,E,S]
  float* sums = (float*)(ws + 80 * MB);  // 4 x 32 KB: s1a,s2a,s1b,s2b
  float* s1a = sums;
  float* s2a = s1a + NROWS;
  float* s1b = s2a + NROWS;
  float* s2b = s1b + NROWS;
  u16* wqt = (u16*)(ws + 80 * MB + 4 * NROWS * sizeof(float));
  u16* wkt = wqt + NHEAD * ESPL * ESPL;
  u16* wvt = wkt + NHEAD * ESPL * ESPL;
  u16* wt2 = wvt + NHEAD * ESPL * ESPL;  // 2 MB Wf^T bf16
  // overlays (lifetimes disjoint, stream-serial):
  u16* wt1 = qb;   // W_in^T bf16: prep -> gemm1; qb written by qkv after gemm1
  u16* xb = kb;    // x bf16: prep -> gemm1; kb written by qkv after gemm1
  u16* modb = qb;  // LN2(mod) bf16: ln_apply -> gemm2; qb dead after attn

  hipMemsetAsync(sums, 0, 4 * NROWS * sizeof(float), stream);
  prep_fused<<<NROWS + 512 + 96, 256, 0, stream>>>(x, xb, W_in, wt1, Wf, wt2, Wq, Wk, Wv, wqt,
                                                   wkt, wvt);

  dim3 gg(DIMN / 128, NROWS / 128);  // (8, 64)
  gemm_bf16<0><<<gg, 256, 0, stream>>>(xb, wt1, nullptr, nullptr, s1a, s2a, mod);
  qkv_mfma<<<dim3(SEQ / 128, NB * NHEAD), 256, 0, stream>>>(mod, wqt, wkt, wvt, gamma, beta,
                                                            s1a, s2a, qb, kb, vtb);
  attn_mfma<<<dim3(SEQ / 128, NB * NHEAD), 256, 0, stream>>>(qb, kb, vtb, mod, s1b, s2b);
  ln_apply<<<NROWS * DIMN / 1024, 256, 0, stream>>>(mod, gamma, beta, s1b, s2b, modb);
  gemm_bf16<1><<<gg, 256, 0, stream>>>(modb, wt2, mod, bf, nullptr, nullptr, out);
}

// Round 8
// 288.226 us; speedup vs baseline: 1.0295x; 1.0295x over previous
//
#include <hip/hip_runtime.h>
#include <hip/hip_bf16.h>

#define DIMN 1024
#define NHEAD 8
#define ESPL 128
#define NB 4
#define SEQ 2048
#define NROWS (NB * SEQ)
#define LNEPS 1e-6f
#define L2E 1.442695041f

typedef unsigned short u16;
typedef unsigned int u32;
typedef __attribute__((ext_vector_type(8))) short short8;
typedef __attribute__((ext_vector_type(4))) short s16x4;
typedef __attribute__((ext_vector_type(4))) float f32x4;

__device__ __forceinline__ u16 f2bf(float f) {
  u32 u = __float_as_uint(f);
  u += 0x7FFFu + ((u >> 16) & 1u);  // round-to-nearest-even
  return (u16)(u >> 16);
}

// single-instruction pack of 2 f32 -> 2 bf16 (RNE), T12 (learn_hip m214v22)
__device__ __forceinline__ u32 pk2bf(float a, float b) {
  u32 r;
  asm("v_cvt_pk_bf16_f32 %0, %1, %2" : "=v"(r) : "v"(a), "v"(b));
  return r;
}

__device__ __forceinline__ uint2 pack4bf(float4 v) {
  uint2 r;
  r.x = pk2bf(v.x, v.y);
  r.y = pk2bf(v.z, v.w);
  return r;
}

// native 2^x (v_exp_f32); gfx9 VALU deps are HW-interlocked so inline asm is safe
__device__ __forceinline__ float fexp2(float x) {
  float r;
  asm("v_exp_f32 %0, %1" : "=v"(r) : "v"(x));
  return r;
}

__device__ __forceinline__ float eluf(float x) { return x > 0.f ? x : expm1f(x); }

// async global->LDS DMA, 16 B per lane; lds dest = wave-uniform base + lane*16
__device__ __forceinline__ void gl2lds16(const u16* g, u16* l) {
  __builtin_amdgcn_global_load_lds((const __attribute__((address_space(1))) u32*)g,
                                   (__attribute__((address_space(3))) u32*)l, 16, 0, 0);
}

// ------- LN apply: modb = bf16(LN(mod)) using precomputed row sums -------
__global__ __launch_bounds__(256) void ln_apply(const float* __restrict__ modp,
                                                const float* __restrict__ gamma,
                                                const float* __restrict__ beta,
                                                const float* __restrict__ s1p,
                                                const float* __restrict__ s2p,
                                                u16* __restrict__ outb) {
  int base = (blockIdx.x * 256 + threadIdx.x) * 4;
  int row = base >> 10, col = base & 1023;
  float s1 = s1p[row], s2 = s2p[row];
  float mu = s1 * (1.f / DIMN);
  float rsd = rsqrtf(fmaxf(s2 * (1.f / DIMN) - mu * mu, 0.f) + LNEPS);
  float4 v = *(const float4*)(modp + base);
  float4 g = *(const float4*)(gamma + col);
  float4 bb = *(const float4*)(beta + col);
  v.x = (v.x - mu) * rsd * g.x + bb.x;
  v.y = (v.y - mu) * rsd * g.y + bb.y;
  v.z = (v.z - mu) * rsd * g.z + bb.z;
  v.w = (v.w - mu) * rsd * g.w + bb.w;
  *(uint2*)(outb + base) = pack4bf(v);
}

// ------- weight transpose + fp32->bf16: dst[n*K+k] = bf16(src[k*N+n]) -------
__device__ __forceinline__ void wtrans_body(u16 (*tl)[68], const float* __restrict__ src,
                                            u16* __restrict__ dst, int K, int N, int n0,
                                            int k0) {
  const int t = threadIdx.x;
  const int r = t >> 2;
#pragma unroll
  for (int j = 0; j < 4; j++) {
    int f = (t & 3) + j * 4;
    float4 v = *(const float4*)(src + (size_t)(k0 + r) * N + n0 + f * 4);
    *(uint2*)&tl[r][f * 4] = pack4bf(v);
  }
  __syncthreads();
#pragma unroll
  for (int j = 0; j < 4; j++) {
    int f = (t & 3) + j * 4;
    ushort4 o;
    o.x = tl[f * 4 + 0][r];
    o.y = tl[f * 4 + 1][r];
    o.z = tl[f * 4 + 2][r];
    o.w = tl[f * 4 + 3][r];
    *(ushort4*)(dst + (size_t)(n0 + r) * K + k0 + f * 4) = o;
  }
}

// ------- fused prep: x->bf16 convert + all weight transposes in ONE launch -----
__global__ __launch_bounds__(256) void prep_fused(
    const float* __restrict__ x, u16* __restrict__ xb, const float* __restrict__ W_in,
    u16* __restrict__ wt1, const float* __restrict__ Wf, u16* __restrict__ wt2,
    const float* __restrict__ Wq, const float* __restrict__ Wk, const float* __restrict__ Wv,
    u16* __restrict__ dq, u16* __restrict__ dk, u16* __restrict__ dv) {
  __shared__ u16 tl[64][68];
  const int bid = blockIdx.x;
  if (bid < NROWS) {
    int base = (bid * 256 + threadIdx.x) * 4;
    *(uint2*)(xb + base) = pack4bf(*(const float4*)(x + base));
  } else if (bid < NROWS + 512) {
    int z = bid - NROWS;
    const float* s = (z & 256) ? Wf : W_in;
    u16* d = (z & 256) ? wt2 : wt1;
    z &= 255;
    wtrans_body(tl, s, d, DIMN, DIMN, (z & 15) * 64, (z >> 4) * 64);
  } else {
    int z = bid - NROWS - 512;  // 0..95
    int xy = z & 3, zz = z >> 2;
    int mi = zz >> 3, hh = zz & 7;
    const float* s = (mi == 0) ? Wq : (mi == 1) ? Wk : Wv;
    u16* d = (mi == 0) ? dq : (mi == 1) ? dk : dv;
    s += (size_t)hh * ESPL * ESPL;
    d += (size_t)hh * ESPL * ESPL;
    wtrans_body(tl, s, d, ESPL, ESPL, (xy & 1) * 64, (xy >> 1) * 64);
  }
}

// ------- pure-bf16 MFMA GEMM: async-DMA double-buffered, 128x128 tile, BK=64 -------
template <int MODE>
__global__ __launch_bounds__(256, 2) void gemm_bf16(
    const u16* __restrict__ A, const u16* __restrict__ Bt, const float* __restrict__ resid,
    const float* __restrict__ bias, float* __restrict__ s1p, float* __restrict__ s2p,
    float* __restrict__ C) {
  __shared__ __align__(16) char lds[65536];  // [As0|Bs0|As1|Bs1] 16 KB each
  const int t = threadIdx.x;
  const int w = t >> 6, lane = t & 63, quad = lane >> 4, l16 = lane & 15;
  const int wm = w & 1, wn = w >> 1;
  const int lin = blockIdx.x + gridDim.x * blockIdx.y;  // 0..511
  const int xcd = lin & 7, slot = lin >> 3;             // 64 slots per XCD
  const int m0 = (xcd * 8 + (slot >> 3)) * 128;
  const int n0 = (slot & 7) * 128;

  auto stage = [&](int koff, int bi) {
    const u16* ag = A + (size_t)m0 * DIMN + koff;
    const u16* bg = Bt + (size_t)n0 * DIMN + koff;
    u16* As = (u16*)(lds + bi * 32768);
    u16* Bs = (u16*)(lds + bi * 32768 + 16384);
#pragma unroll
    for (int i = 0; i < 4; i++) {
      int pbase = (w * 4 + i) * 64;
      int p = pbase + lane;
      int r = p >> 3, c8 = (p & 7) ^ (r & 7);
      gl2lds16(ag + (size_t)r * DIMN + c8 * 8, As + pbase * 8);
      gl2lds16(bg + (size_t)r * DIMN + c8 * 8, Bs + pbase * 8);
    }
  };

  f32x4 acc[4][4];
#pragma unroll
  for (int mt = 0; mt < 4; mt++)
#pragma unroll
    for (int nt = 0; nt < 4; nt++) acc[mt][nt] = (f32x4){0.f, 0.f, 0.f, 0.f};

  stage(0, 0);
  __syncthreads();
  for (int kt = 0; kt < DIMN / 64; kt++) {
    if (kt + 1 < DIMN / 64) stage((kt + 1) * 64, (kt + 1) & 1);
    const u16* As = (const u16*)(lds + (kt & 1) * 32768);
    const u16* Bs = (const u16*)(lds + (kt & 1) * 32768 + 16384);
#pragma unroll
    for (int ks = 0; ks < 2; ks++) {
      short8 af[4], bfr[4];
#pragma unroll
      for (int mt = 0; mt < 4; mt++) {
        int row = wm * 64 + mt * 16 + l16;
        int pc = (ks * 4 + quad) ^ (row & 7);
        af[mt] = *(const short8*)(As + row * 64 + pc * 8);
      }
#pragma unroll
      for (int nt = 0; nt < 4; nt++) {
        int row = wn * 64 + nt * 16 + l16;
        int pc = (ks * 4 + quad) ^ (row & 7);
        bfr[nt] = *(const short8*)(Bs + row * 64 + pc * 8);
      }
#pragma unroll
      for (int mt = 0; mt < 4; mt++)
#pragma unroll
        for (int nt = 0; nt < 4; nt++)
          acc[mt][nt] = __builtin_amdgcn_mfma_f32_16x16x32_bf16(bfr[nt], af[mt], acc[mt][nt], 0, 0, 0);
    }
    __syncthreads();
  }
  // epilogue: row m = ..+l16 (quad-invariant); cols n = ..+quad*4+r
#pragma unroll
  for (int mt = 0; mt < 4; mt++) {
    int row = m0 + wm * 64 + mt * 16 + l16;
    float s1 = 0.f, s2 = 0.f;
#pragma unroll
    for (int nt = 0; nt < 4; nt++) {
      int col = n0 + wn * 64 + nt * 16 + quad * 4;
      size_t off = (size_t)row * DIMN + col;
      f32x4 v = acc[mt][nt];
      if (MODE == 0) {
        *(f32x4*)(C + off) = v;
        s1 += (v[0] + v[1]) + (v[2] + v[3]);
        s2 += (v[0] * v[0] + v[1] * v[1]) + (v[2] * v[2] + v[3] * v[3]);
      } else {
        float4 rv = *(const float4*)(resid + off);
        float4 bv = *(const float4*)(bias + col);
        float4 o;
        o.x = rv.x + eluf(v[0] + bv.x);
        o.y = rv.y + eluf(v[1] + bv.y);
        o.z = rv.z + eluf(v[2] + bv.z);
        o.w = rv.w + eluf(v[3] + bv.w);
        *(float4*)(C + off) = o;
      }
    }
    if (MODE == 0) {
      s1 += __shfl_xor(s1, 16);
      s1 += __shfl_xor(s1, 32);
      s2 += __shfl_xor(s2, 16);
      s2 += __shfl_xor(s2, 32);
      if (quad == 0) {
        atomicAdd(s1p + row, s1);
        atomicAdd(s2p + row, s2);
      }
    }
  }
}

// ------- QKV: per (b,h), 128 s-rows x 128 e, K=128; LN1 fused in A-staging -------
#define QP 136

__global__ __launch_bounds__(256) void qkv_mfma(
    const float* __restrict__ modp, const u16* __restrict__ wqt, const u16* __restrict__ wkt,
    const u16* __restrict__ wvt, const float* __restrict__ gamma, const float* __restrict__ beta,
    const float* __restrict__ s1p, const float* __restrict__ s2p, u16* __restrict__ qo,
    u16* __restrict__ ko, u16* __restrict__ vto) {
  __shared__ u16 Asl[128 * QP];
  __shared__ u16 Bsl[128 * QP];
  const int t = threadIdx.x;
  const int w = t >> 6, lane = t & 63, quad = lane >> 4, l16 = lane & 15;
  const int wm = w & 1, wn = w >> 1;
  const int lin = blockIdx.x + gridDim.x * blockIdx.y;  // 0..511
  const int xcd = lin & 7, slot = lin >> 3;
  const int s0 = (slot >> 2) * 128;
  const int bh = (slot & 3) * 8 + xcd;  // hh == xcd
  const int b = bh >> 3, hh = bh & 7;
  const int sr8 = t >> 3, sf8 = t & 7;
#pragma unroll
  for (int p = 0; p < 4; p++) {
    int r = sr8 + 32 * p;
    int rowg = b * SEQ + s0 + r;
    float s1 = s1p[rowg], s2 = s2p[rowg];
    float mu = s1 * (1.f / DIMN);
    float rsd = rsqrtf(fmaxf(s2 * (1.f / DIMN) - mu * mu, 0.f) + LNEPS);
    const float* ap = modp + (size_t)rowg * DIMN + hh * ESPL;
#pragma unroll
    for (int j = 0; j < 4; j++) {
      int f = sf8 + j * 8;
      float4 v = *(const float4*)(ap + f * 4);
      float4 g = *(const float4*)(gamma + hh * ESPL + f * 4);
      float4 bb = *(const float4*)(beta + hh * ESPL + f * 4);
      v.x = (v.x - mu) * rsd * g.x + bb.x;
      v.y = (v.y - mu) * rsd * g.y + bb.y;
      v.z = (v.z - mu) * rsd * g.z + bb.z;
      v.w = (v.w - mu) * rsd * g.w + bb.w;
      *(uint2*)(Asl + r * QP + f * 4) = pack4bf(v);
    }
  }
  __syncthreads();
  short8 afr[4][4];
#pragma unroll
  for (int k4 = 0; k4 < 4; k4++)
#pragma unroll
    for (int mt = 0; mt < 4; mt++)
      afr[k4][mt] = *(const short8*)(Asl + (wm * 64 + mt * 16 + l16) * QP + k4 * 32 + quad * 8);

  const u16* Ws[3] = {wqt, wkt, wvt};
  for (int mi = 0; mi < 3; mi++) {
    __syncthreads();
    const u16* wsrc = Ws[mi] + ((size_t)hh << 14);
#pragma unroll
    for (int p = 0; p < 4; p++) {
      int r = sr8 + 32 * p;
#pragma unroll
      for (int j = 0; j < 2; j++) {
        int f = sf8 + j * 8;
        *(uint4*)(Bsl + r * QP + f * 8) = *(const uint4*)(wsrc + r * ESPL + f * 8);
      }
    }
    __syncthreads();
    f32x4 acc[4][4];
#pragma unroll
    for (int mt = 0; mt < 4; mt++)
#pragma unroll
      for (int nt = 0; nt < 4; nt++) acc[mt][nt] = (f32x4){0.f, 0.f, 0.f, 0.f};
#pragma unroll
    for (int k4 = 0; k4 < 4; k4++) {
      short8 bfr[4];
#pragma unroll
      for (int nt = 0; nt < 4; nt++)
        bfr[nt] = *(const short8*)(Bsl + (wn * 64 + nt * 16 + l16) * QP + k4 * 32 + quad * 8);
      if (mi < 2) {
#pragma unroll
        for (int mt = 0; mt < 4; mt++)
#pragma unroll
          for (int nt = 0; nt < 4; nt++)
            acc[mt][nt] = __builtin_amdgcn_mfma_f32_16x16x32_bf16(bfr[nt], afr[k4][mt], acc[mt][nt], 0, 0, 0);
      } else {
#pragma unroll
        for (int mt = 0; mt < 4; mt++)
#pragma unroll
          for (int nt = 0; nt < 4; nt++)
            acc[mt][nt] = __builtin_amdgcn_mfma_f32_16x16x32_bf16(afr[k4][mt], bfr[nt], acc[mt][nt], 0, 0, 0);
      }
    }
    if (mi < 2) {
      u16* o = (mi == 0) ? qo : ko;
#pragma unroll
      for (int mt = 0; mt < 4; mt++) {
        int s = s0 + wm * 64 + mt * 16 + l16;
#pragma unroll
        for (int nt = 0; nt < 4; nt++) {
          int e0 = wn * 64 + nt * 16 + quad * 4;
          uint2 pk;
          pk.x = pk2bf(acc[mt][nt][0], acc[mt][nt][1]);
          pk.y = pk2bf(acc[mt][nt][2], acc[mt][nt][3]);
          *(uint2*)(o + ((size_t)bh * SEQ + s) * ESPL + e0) = pk;
        }
      }
    } else {
#pragma unroll
      for (int mt = 0; mt < 4; mt++)
#pragma unroll
        for (int nt = 0; nt < 4; nt++) {
          int e = wn * 64 + nt * 16 + l16;
          int sbase = s0 + wm * 64 + mt * 16 + quad * 4;
          uint2 pk;
          pk.x = pk2bf(acc[mt][nt][0], acc[mt][nt][1]);
          pk.y = pk2bf(acc[mt][nt][2], acc[mt][nt][3]);
          *(uint2*)(vto + ((size_t)bh * ESPL + e) * SEQ + sbase) = pk;
        }
    }
  }
}

// ------- MFMA flash attention v11: v10 data paths, 8 waves x 16 q-rows -------
// Same block tile (128 q), same LDS layouts/swizzles/sync (K/V dbuf, 1 barrier
// per tile), but 512 threads: wave w owns q-rows [qt*128+w*16, +16). 2x waves
// per SIMD (4) -> latency of the serial QK^T->softmax->PV chain hides via TLP.
#define OBP 132  // epilogue Obuf pitch (f32)
#define RESCALE_THR 8.f

__global__ __launch_bounds__(512, 4) void attn_mfma(const u16* __restrict__ q,
                                                    const u16* __restrict__ kk,
                                                    const u16* __restrict__ vt,
                                                    float* __restrict__ modp,
                                                    float* __restrict__ s1p,
                                                    float* __restrict__ s2p) {
  // [Ks0|Vs0|Ks1|Vs1] 16 KB each + 16 KB P^T scratch (2 KB/wave x 8) = 80 KB
  __shared__ __align__(16) char lds[81920];
  const int t = threadIdx.x;
  const int w = t >> 6, lane = t & 63, quad = lane >> 4, l16 = lane & 15;
  const int lin = blockIdx.x + gridDim.x * blockIdx.y;  // 0..511
  const int xcd = lin & 7, slot = lin >> 3;             // 64 slots per XCD
  const int qt = slot & 15;                             // 0..15
  const int bh = xcd * 4 + (slot >> 4);                 // 4 bh per XCD
  const int b = bh >> 3, hh = bh & 7;
  const size_t qkbase = (size_t)bh * SEQ * ESPL;
  const int qrow0 = qt * 128 + w * 16;  // 16 q-rows per wave
  const u16* kg0 = kk + qkbase;
  const u16* vg0 = vt + qkbase;
  // per-wave P^T scratch: P_t[q=l16][k 0..63] bf16, 16B-XOR-swizzled rows
  char* Pt = lds + 65536 + w * 2048;
  const int swz = (l16 & 7) << 4;

  short8 qf[4];
  {
    const u16* qrow = q + qkbase + (size_t)(qrow0 + l16) * ESPL + quad * 8;
#pragma unroll
    for (int kc = 0; kc < 4; kc++) qf[kc] = *(const short8*)(qrow + kc * 32);
  }

  float m_st = -1e30f, l_st = 0.f;
  f32x4 oacc[8];
#pragma unroll
  for (int et = 0; et < 8; et++) oacc[et] = (f32x4){0.f, 0.f, 0.f, 0.f};

  auto stage = [&](int kt, int bi) {
    const u16* kg = kg0 + (size_t)kt * 64 * ESPL;
    const u16* vg = vg0 + (size_t)kt * 64;
    u16* Ksb = (u16*)(lds + bi * 32768);
    u16* Vsb = (u16*)(lds + bi * 32768 + 16384);
#pragma unroll
    for (int i = 0; i < 2; i++) {
      int pbase = w * 128 + i * 64;
      int p = pbase + lane;
      int r = p >> 4, c8 = (p & 15) ^ (r & 15);
      gl2lds16(kg + r * ESPL + c8 * 8, Ksb + pbase * 8);
      int e = p >> 3, v8 = (p & 7) ^ (e & 7);
      gl2lds16(vg + (size_t)e * SEQ + v8 * 8, Vsb + pbase * 8);
    }
  };

  stage(0, 0);
  __syncthreads();

  for (int kt = 0; kt < SEQ / 64; kt++) {
    if (kt + 1 < SEQ / 64) stage(kt + 1, (kt + 1) & 1);
    const u16* Ks = (const u16*)(lds + (kt & 1) * 32768);
    const u16* Vs = (const u16*)(lds + (kt & 1) * 32768 + 16384);
    f32x4 sacc[4];
#pragma unroll
    for (int mt = 0; mt < 4; mt++) sacc[mt] = (f32x4){0.f, 0.f, 0.f, 0.f};
    __builtin_amdgcn_s_setprio(1);
#pragma unroll
    for (int mt = 0; mt < 4; mt++) {
#pragma unroll
      for (int kc = 0; kc < 4; kc++) {
        short8 kf = *(const short8*)(Ks + (mt * 16 + l16) * 128 + (((kc * 4 + quad) ^ l16) << 3));
        sacc[mt] = __builtin_amdgcn_mfma_f32_16x16x32_bf16(kf, qf[kc], sacc[mt], 0, 0, 0);
      }
    }
    __builtin_amdgcn_s_setprio(0);
    // tree reduce over the 16 local S values (depth 3)
    {
      const f32x4 a = sacc[0], b2 = sacc[1], c2 = sacc[2], d2 = sacc[3];
      float t0 = fmaxf(fmaxf(a[0], a[1]), a[2]);
      float t1 = fmaxf(fmaxf(a[3], b2[0]), b2[1]);
      float t2 = fmaxf(fmaxf(b2[2], b2[3]), c2[0]);
      float t3 = fmaxf(fmaxf(c2[1], c2[2]), c2[3]);
      float t4 = fmaxf(fmaxf(d2[0], d2[1]), d2[2]);
      float mloc = fmaxf(fmaxf(fmaxf(t0, t1), t2), fmaxf(fmaxf(t3, t4), d2[3]));
      mloc = fmaxf(mloc, __shfl_xor(mloc, 16));
      mloc = fmaxf(mloc, __shfl_xor(mloc, 32));
      // defer-max (T13)
      bool updf = !__all(mloc - m_st <= RESCALE_THR);
      float alpha = 1.f;
      if (updf) {
        float mnew = fmaxf(m_st, mloc);
        alpha = fexp2((m_st - mnew) * L2E);
        m_st = mnew;
      }
      const float mkn = -m_st * L2E;  // fold max-subtract into the exp2 fma
      float sum = 0.f;
#pragma unroll
      for (int mt = 0; mt < 4; mt++) {
        float p0 = fexp2(fmaf(sacc[mt][0], L2E, mkn));
        float p1 = fexp2(fmaf(sacc[mt][1], L2E, mkn));
        float p2 = fexp2(fmaf(sacc[mt][2], L2E, mkn));
        float p3 = fexp2(fmaf(sacc[mt][3], L2E, mkn));
        sum += (p0 + p1) + (p2 + p3);
        uint2 pkv = make_uint2(pk2bf(p0, p1), pk2bf(p2, p3));
        // P^T[q=l16][k = mt*16 + quad*4 + 0..3] (bf16), 16B-granular XOR swizzle
        *(uint2*)(Pt + l16 * 128 + ((mt * 32 + quad * 8) ^ swz)) = pkv;
      }
      sum += __shfl_xor(sum, 16);
      sum += __shfl_xor(sum, 32);
      l_st = l_st * alpha + sum;
      if (updf) {  // wave-uniform branch (from __all)
#pragma unroll
        for (int et = 0; et < 8; et++)
#pragma unroll
          for (int r = 0; r < 4; r++) oacc[et][r] *= alpha;
      }
    }
    // B-fragments for 16x16x32 PV: one contiguous b128 from own P^T row
    short8 pb[2];
#pragma unroll
    for (int mtp = 0; mtp < 2; mtp++)
      pb[mtp] = *(const short8*)(Pt + l16 * 128 + ((mtp * 64 + quad * 16) ^ swz));
    __builtin_amdgcn_s_setprio(1);
#pragma unroll
    for (int et = 0; et < 8; et++) {
#pragma unroll
      for (int mtp = 0; mtp < 2; mtp++) {
        short8 vf8 = *(const short8*)(Vs + (size_t)(et * 16 + l16) * 64 +
                                      (((mtp * 4 + quad) ^ (l16 & 7)) << 3));
        oacc[et] = __builtin_amdgcn_mfma_f32_16x16x32_bf16(vf8, pb[mtp], oacc[et], 0, 0, 0);
      }
    }
    __builtin_amdgcn_s_setprio(0);
    __syncthreads();  // drains DMA + all waves done reading this buffer
  }

  // single-barrier epilogue: wave w owns Obuf rows [w*16, w*16+16)
  float* Obuf = (float*)lds;
  {
    float linv = 1.f / l_st;
    float* Ow = Obuf + (size_t)w * 16 * OBP;
#pragma unroll
    for (int et = 0; et < 8; et++) {
      f32x4 ov = oacc[et];
      ov[0] *= linv;
      ov[1] *= linv;
      ov[2] *= linv;
      ov[3] *= linv;
      *(f32x4*)(Ow + (size_t)l16 * OBP + et * 16 + quad * 4) = ov;
    }
  }
  __syncthreads();
  // drain: 512 threads, 128 rows x 128 cols; 4 threads per row, 32 f32 each
  const int rr = t >> 2, cc = (t & 3) << 5;
  int qglob = qt * 128 + rr;
  float* mp = modp + ((size_t)(b * SEQ + qglob)) * DIMN + hh * ESPL + cc;
  const float* Oc = Obuf + (size_t)rr * OBP + cc;
  float s1 = 0.f, s2 = 0.f;
#pragma unroll
  for (int j = 0; j < 8; j++) {
    float4 ov = *(const float4*)(Oc + j * 4);
    float4 mv = *(const float4*)(mp + j * 4);
    mv.x += ov.x;
    mv.y += ov.y;
    mv.z += ov.z;
    mv.w += ov.w;
    *(float4*)(mp + j * 4) = mv;
    s1 += (mv.x + mv.y) + (mv.z + mv.w);
    s2 += (mv.x * mv.x + mv.y * mv.y) + (mv.z * mv.z + mv.w * mv.w);
  }
  s1 += __shfl_xor(s1, 1);
  s1 += __shfl_xor(s1, 2);
  s2 += __shfl_xor(s2, 1);
  s2 += __shfl_xor(s2, 2);
  if ((t & 3) == 0) {
    atomicAdd(s1p + b * SEQ + qglob, s1);
    atomicAdd(s2p + b * SEQ + qglob, s2);
  }
}

extern "C" void kernel_launch(void* const* d_in, const int* in_sizes, int n_in, void* d_out,
                              int out_size, void* d_ws, size_t ws_size, hipStream_t stream) {
  (void)in_sizes;
  (void)n_in;
  (void)out_size;
  (void)ws_size;
  const float* x = (const float*)d_in[0];
  const float* W_in = (const float*)d_in[1];
  const float* gamma = (const float*)d_in[2];
  const float* beta = (const float*)d_in[3];
  const float* Wq = (const float*)d_in[4];
  const float* Wk = (const float*)d_in[5];
  const float* Wv = (const float*)d_in[6];
  const float* Wf = (const float*)d_in[7];
  const float* bf = (const float*)d_in[8];
  float* out = (float*)d_out;

  char* ws = (char*)d_ws;
  const size_t MB = 1024ull * 1024;
  float* mod = (float*)ws;               // 32 MB fp32 [8192,1024]
  u16* qb = (u16*)(ws + 32 * MB);        // 16 MB bf16 [B,H,S,E]
  u16* kb = (u16*)(ws + 48 * MB);        // 16 MB bf16 [B,H,S,E]
  u16* vtb = (u16*)(ws + 64 * MB);       // 16 MB bf16 [B,H,E,S]
  float* sums = (float*)(ws + 80 * MB);  // 4 x 32 KB: s1a,s2a,s1b,s2b
  float* s1a = sums;
  float* s2a = s1a + NROWS;
  float* s1b = s2a + NROWS;
  float* s2b = s1b + NROWS;
  u16* wqt = (u16*)(ws + 80 * MB + 4 * NROWS * sizeof(float));
  u16* wkt = wqt + NHEAD * ESPL * ESPL;
  u16* wvt = wkt + NHEAD * ESPL * ESPL;
  u16* wt2 = wvt + NHEAD * ESPL * ESPL;  // 2 MB Wf^T bf16
  // overlays (lifetimes disjoint, stream-serial):
  u16* wt1 = qb;   // W_in^T bf16: prep -> gemm1; qb written by qkv after gemm1
  u16* xb = kb;    // x bf16: prep -> gemm1; kb written by qkv after gemm1
  u16* modb = qb;  // LN2(mod) bf16: ln_apply -> gemm2; qb dead after attn

  hipMemsetAsync(sums, 0, 4 * NROWS * sizeof(float), stream);
  prep_fused<<<NROWS + 512 + 96, 256, 0, stream>>>(x, xb, W_in, wt1, Wf, wt2, Wq, Wk, Wv, wqt,
                                                   wkt, wvt);

  dim3 gg(DIMN / 128, NROWS / 128);  // (8, 64)
  gemm_bf16<0><<<gg, 256, 0, stream>>>(xb, wt1, nullptr, nullptr, s1a, s2a, mod);
  qkv_mfma<<<dim3(SEQ / 128, NB * NHEAD), 256, 0, stream>>>(mod, wqt, wkt, wvt, gamma, beta,
                                                            s1a, s2a, qb, kb, vtb);
  attn_mfma<<<dim3(SEQ / 128, NB * NHEAD), 512, 0, stream>>>(qb, kb, vtb, mod, s1b, s2b);
  ln_apply<<<NROWS * DIMN / 1024, 256, 0, stream>>>(mod, gamma, beta, s1b, s2b, modb);
  gemm_bf16<1><<<gg, 256, 0, stream>>>(modb, wt2, mod, bf, nullptr, nullptr, out);
}

// Round 9
// 284.935 us; speedup vs baseline: 1.0414x; 1.0115x over previous
//
#include <hip/hip_runtime.h>
#include <hip/hip_bf16.h>

#define DIMN 1024
#define NHEAD 8
#define ESPL 128
#define NB 4
#define SEQ 2048
#define NROWS (NB * SEQ)
#define LNEPS 1e-6f
#define L2E 1.442695041f

typedef unsigned short u16;
typedef unsigned int u32;
typedef __attribute__((ext_vector_type(8))) short short8;
typedef __attribute__((ext_vector_type(4))) short s16x4;
typedef __attribute__((ext_vector_type(4))) float f32x4;

__device__ __forceinline__ u16 f2bf(float f) {
  u32 u = __float_as_uint(f);
  u += 0x7FFFu + ((u >> 16) & 1u);  // round-to-nearest-even
  return (u16)(u >> 16);
}

// single-instruction pack of 2 f32 -> 2 bf16 (RNE), T12 (learn_hip m214v22)
__device__ __forceinline__ u32 pk2bf(float a, float b) {
  u32 r;
  asm("v_cvt_pk_bf16_f32 %0, %1, %2" : "=v"(r) : "v"(a), "v"(b));
  return r;
}

__device__ __forceinline__ uint2 pack4bf(float4 v) {
  uint2 r;
  r.x = pk2bf(v.x, v.y);
  r.y = pk2bf(v.z, v.w);
  return r;
}

// native 2^x (v_exp_f32); gfx9 VALU deps are HW-interlocked so inline asm is safe
__device__ __forceinline__ float fexp2(float x) {
  float r;
  asm("v_exp_f32 %0, %1" : "=v"(r) : "v"(x));
  return r;
}

__device__ __forceinline__ float eluf(float x) { return x > 0.f ? x : expm1f(x); }

// async global->LDS DMA, 16 B per lane; lds dest = wave-uniform base + lane*16
__device__ __forceinline__ void gl2lds16(const u16* g, u16* l) {
  __builtin_amdgcn_global_load_lds((const __attribute__((address_space(1))) u32*)g,
                                   (__attribute__((address_space(3))) u32*)l, 16, 0, 0);
}

// ------- LN apply: modb = bf16(LN(mod)) using precomputed row sums -------
__global__ __launch_bounds__(256) void ln_apply(const float* __restrict__ modp,
                                                const float* __restrict__ gamma,
                                                const float* __restrict__ beta,
                                                const float* __restrict__ s1p,
                                                const float* __restrict__ s2p,
                                                u16* __restrict__ outb) {
  int base = (blockIdx.x * 256 + threadIdx.x) * 4;
  int row = base >> 10, col = base & 1023;
  float s1 = s1p[row], s2 = s2p[row];
  float mu = s1 * (1.f / DIMN);
  float rsd = rsqrtf(fmaxf(s2 * (1.f / DIMN) - mu * mu, 0.f) + LNEPS);
  float4 v = *(const float4*)(modp + base);
  float4 g = *(const float4*)(gamma + col);
  float4 bb = *(const float4*)(beta + col);
  v.x = (v.x - mu) * rsd * g.x + bb.x;
  v.y = (v.y - mu) * rsd * g.y + bb.y;
  v.z = (v.z - mu) * rsd * g.z + bb.z;
  v.w = (v.w - mu) * rsd * g.w + bb.w;
  *(uint2*)(outb + base) = pack4bf(v);
}

// ------- weight transpose + fp32->bf16: dst[n*K+k] = bf16(src[k*N+n]) -------
__device__ __forceinline__ void wtrans_body(u16 (*tl)[68], const float* __restrict__ src,
                                            u16* __restrict__ dst, int K, int N, int n0,
                                            int k0) {
  const int t = threadIdx.x;
  const int r = t >> 2;
#pragma unroll
  for (int j = 0; j < 4; j++) {
    int f = (t & 3) + j * 4;
    float4 v = *(const float4*)(src + (size_t)(k0 + r) * N + n0 + f * 4);
    *(uint2*)&tl[r][f * 4] = pack4bf(v);
  }
  __syncthreads();
#pragma unroll
  for (int j = 0; j < 4; j++) {
    int f = (t & 3) + j * 4;
    ushort4 o;
    o.x = tl[f * 4 + 0][r];
    o.y = tl[f * 4 + 1][r];
    o.z = tl[f * 4 + 2][r];
    o.w = tl[f * 4 + 3][r];
    *(ushort4*)(dst + (size_t)(n0 + r) * K + k0 + f * 4) = o;
  }
}

// ------- fused prep: x->bf16 convert + all weight transposes in ONE launch -----
__global__ __launch_bounds__(256) void prep_fused(
    const float* __restrict__ x, u16* __restrict__ xb, const float* __restrict__ W_in,
    u16* __restrict__ wt1, const float* __restrict__ Wf, u16* __restrict__ wt2,
    const float* __restrict__ Wq, const float* __restrict__ Wk, const float* __restrict__ Wv,
    u16* __restrict__ dq, u16* __restrict__ dk, u16* __restrict__ dv) {
  __shared__ u16 tl[64][68];
  const int bid = blockIdx.x;
  if (bid < NROWS) {
    int base = (bid * 256 + threadIdx.x) * 4;
    *(uint2*)(xb + base) = pack4bf(*(const float4*)(x + base));
  } else if (bid < NROWS + 512) {
    int z = bid - NROWS;
    const float* s = (z & 256) ? Wf : W_in;
    u16* d = (z & 256) ? wt2 : wt1;
    z &= 255;
    wtrans_body(tl, s, d, DIMN, DIMN, (z & 15) * 64, (z >> 4) * 64);
  } else {
    int z = bid - NROWS - 512;  // 0..95
    int xy = z & 3, zz = z >> 2;
    int mi = zz >> 3, hh = zz & 7;
    const float* s = (mi == 0) ? Wq : (mi == 1) ? Wk : Wv;
    u16* d = (mi == 0) ? dq : (mi == 1) ? dk : dv;
    s += (size_t)hh * ESPL * ESPL;
    d += (size_t)hh * ESPL * ESPL;
    wtrans_body(tl, s, d, ESPL, ESPL, (xy & 1) * 64, (xy >> 1) * 64);
  }
}

// ------- pure-bf16 MFMA GEMM: async-DMA double-buffered, 128x128 tile, BK=64 -------
template <int MODE>
__global__ __launch_bounds__(256, 2) void gemm_bf16(
    const u16* __restrict__ A, const u16* __restrict__ Bt, const float* __restrict__ resid,
    const float* __restrict__ bias, float* __restrict__ s1p, float* __restrict__ s2p,
    float* __restrict__ C) {
  __shared__ __align__(16) char lds[65536];  // [As0|Bs0|As1|Bs1] 16 KB each
  const int t = threadIdx.x;
  const int w = t >> 6, lane = t & 63, quad = lane >> 4, l16 = lane & 15;
  const int wm = w & 1, wn = w >> 1;
  const int lin = blockIdx.x + gridDim.x * blockIdx.y;  // 0..511
  const int xcd = lin & 7, slot = lin >> 3;             // 64 slots per XCD
  const int m0 = (xcd * 8 + (slot >> 3)) * 128;
  const int n0 = (slot & 7) * 128;

  auto stage = [&](int koff, int bi) {
    const u16* ag = A + (size_t)m0 * DIMN + koff;
    const u16* bg = Bt + (size_t)n0 * DIMN + koff;
    u16* As = (u16*)(lds + bi * 32768);
    u16* Bs = (u16*)(lds + bi * 32768 + 16384);
#pragma unroll
    for (int i = 0; i < 4; i++) {
      int pbase = (w * 4 + i) * 64;
      int p = pbase + lane;
      int r = p >> 3, c8 = (p & 7) ^ (r & 7);
      gl2lds16(ag + (size_t)r * DIMN + c8 * 8, As + pbase * 8);
      gl2lds16(bg + (size_t)r * DIMN + c8 * 8, Bs + pbase * 8);
    }
  };

  f32x4 acc[4][4];
#pragma unroll
  for (int mt = 0; mt < 4; mt++)
#pragma unroll
    for (int nt = 0; nt < 4; nt++) acc[mt][nt] = (f32x4){0.f, 0.f, 0.f, 0.f};

  stage(0, 0);
  __syncthreads();
  for (int kt = 0; kt < DIMN / 64; kt++) {
    if (kt + 1 < DIMN / 64) stage((kt + 1) * 64, (kt + 1) & 1);
    const u16* As = (const u16*)(lds + (kt & 1) * 32768);
    const u16* Bs = (const u16*)(lds + (kt & 1) * 32768 + 16384);
#pragma unroll
    for (int ks = 0; ks < 2; ks++) {
      short8 af[4], bfr[4];
#pragma unroll
      for (int mt = 0; mt < 4; mt++) {
        int row = wm * 64 + mt * 16 + l16;
        int pc = (ks * 4 + quad) ^ (row & 7);
        af[mt] = *(const short8*)(As + row * 64 + pc * 8);
      }
#pragma unroll
      for (int nt = 0; nt < 4; nt++) {
        int row = wn * 64 + nt * 16 + l16;
        int pc = (ks * 4 + quad) ^ (row & 7);
        bfr[nt] = *(const short8*)(Bs + row * 64 + pc * 8);
      }
#pragma unroll
      for (int mt = 0; mt < 4; mt++)
#pragma unroll
        for (int nt = 0; nt < 4; nt++)
          acc[mt][nt] = __builtin_amdgcn_mfma_f32_16x16x32_bf16(bfr[nt], af[mt], acc[mt][nt], 0, 0, 0);
    }
    __syncthreads();
  }
  // epilogue: row m = ..+l16 (quad-invariant); cols n = ..+quad*4+r
#pragma unroll
  for (int mt = 0; mt < 4; mt++) {
    int row = m0 + wm * 64 + mt * 16 + l16;
    float s1 = 0.f, s2 = 0.f;
#pragma unroll
    for (int nt = 0; nt < 4; nt++) {
      int col = n0 + wn * 64 + nt * 16 + quad * 4;
      size_t off = (size_t)row * DIMN + col;
      f32x4 v = acc[mt][nt];
      if (MODE == 0) {
        *(f32x4*)(C + off) = v;
        s1 += (v[0] + v[1]) + (v[2] + v[3]);
        s2 += (v[0] * v[0] + v[1] * v[1]) + (v[2] * v[2] + v[3] * v[3]);
      } else {
        float4 rv = *(const float4*)(resid + off);
        float4 bv = *(const float4*)(bias + col);
        float4 o;
        o.x = rv.x + eluf(v[0] + bv.x);
        o.y = rv.y + eluf(v[1] + bv.y);
        o.z = rv.z + eluf(v[2] + bv.z);
        o.w = rv.w + eluf(v[3] + bv.w);
        *(float4*)(C + off) = o;
      }
    }
    if (MODE == 0) {
      s1 += __shfl_xor(s1, 16);
      s1 += __shfl_xor(s1, 32);
      s2 += __shfl_xor(s2, 16);
      s2 += __shfl_xor(s2, 32);
      if (quad == 0) {
        atomicAdd(s1p + row, s1);
        atomicAdd(s2p + row, s2);
      }
    }
  }
}

// ------- QKV: per (b,h), 128 s-rows x 128 e, K=128; LN1 fused in A-staging -------
#define QP 136

__global__ __launch_bounds__(256) void qkv_mfma(
    const float* __restrict__ modp, const u16* __restrict__ wqt, const u16* __restrict__ wkt,
    const u16* __restrict__ wvt, const float* __restrict__ gamma, const float* __restrict__ beta,
    const float* __restrict__ s1p, const float* __restrict__ s2p, u16* __restrict__ qo,
    u16* __restrict__ ko, u16* __restrict__ vto) {
  __shared__ u16 Asl[128 * QP];
  __shared__ u16 Bsl[128 * QP];
  const int t = threadIdx.x;
  const int w = t >> 6, lane = t & 63, quad = lane >> 4, l16 = lane & 15;
  const int wm = w & 1, wn = w >> 1;
  const int lin = blockIdx.x + gridDim.x * blockIdx.y;  // 0..511
  const int xcd = lin & 7, slot = lin >> 3;
  const int s0 = (slot >> 2) * 128;
  const int bh = (slot & 3) * 8 + xcd;  // hh == xcd
  const int b = bh >> 3, hh = bh & 7;
  const int sr8 = t >> 3, sf8 = t & 7;
#pragma unroll
  for (int p = 0; p < 4; p++) {
    int r = sr8 + 32 * p;
    int rowg = b * SEQ + s0 + r;
    float s1 = s1p[rowg], s2 = s2p[rowg];
    float mu = s1 * (1.f / DIMN);
    float rsd = rsqrtf(fmaxf(s2 * (1.f / DIMN) - mu * mu, 0.f) + LNEPS);
    const float* ap = modp + (size_t)rowg * DIMN + hh * ESPL;
#pragma unroll
    for (int j = 0; j < 4; j++) {
      int f = sf8 + j * 8;
      float4 v = *(const float4*)(ap + f * 4);
      float4 g = *(const float4*)(gamma + hh * ESPL + f * 4);
      float4 bb = *(const float4*)(beta + hh * ESPL + f * 4);
      v.x = (v.x - mu) * rsd * g.x + bb.x;
      v.y = (v.y - mu) * rsd * g.y + bb.y;
      v.z = (v.z - mu) * rsd * g.z + bb.z;
      v.w = (v.w - mu) * rsd * g.w + bb.w;
      *(uint2*)(Asl + r * QP + f * 4) = pack4bf(v);
    }
  }
  __syncthreads();
  short8 afr[4][4];
#pragma unroll
  for (int k4 = 0; k4 < 4; k4++)
#pragma unroll
    for (int mt = 0; mt < 4; mt++)
      afr[k4][mt] = *(const short8*)(Asl + (wm * 64 + mt * 16 + l16) * QP + k4 * 32 + quad * 8);

  const u16* Ws[3] = {wqt, wkt, wvt};
  for (int mi = 0; mi < 3; mi++) {
    __syncthreads();
    const u16* wsrc = Ws[mi] + ((size_t)hh << 14);
#pragma unroll
    for (int p = 0; p < 4; p++) {
      int r = sr8 + 32 * p;
#pragma unroll
      for (int j = 0; j < 2; j++) {
        int f = sf8 + j * 8;
        *(uint4*)(Bsl + r * QP + f * 8) = *(const uint4*)(wsrc + r * ESPL + f * 8);
      }
    }
    __syncthreads();
    f32x4 acc[4][4];
#pragma unroll
    for (int mt = 0; mt < 4; mt++)
#pragma unroll
      for (int nt = 0; nt < 4; nt++) acc[mt][nt] = (f32x4){0.f, 0.f, 0.f, 0.f};
#pragma unroll
    for (int k4 = 0; k4 < 4; k4++) {
      short8 bfr[4];
#pragma unroll
      for (int nt = 0; nt < 4; nt++)
        bfr[nt] = *(const short8*)(Bsl + (wn * 64 + nt * 16 + l16) * QP + k4 * 32 + quad * 8);
      if (mi < 2) {
#pragma unroll
        for (int mt = 0; mt < 4; mt++)
#pragma unroll
          for (int nt = 0; nt < 4; nt++)
            acc[mt][nt] = __builtin_amdgcn_mfma_f32_16x16x32_bf16(bfr[nt], afr[k4][mt], acc[mt][nt], 0, 0, 0);
      } else {
#pragma unroll
        for (int mt = 0; mt < 4; mt++)
#pragma unroll
          for (int nt = 0; nt < 4; nt++)
            acc[mt][nt] = __builtin_amdgcn_mfma_f32_16x16x32_bf16(afr[k4][mt], bfr[nt], acc[mt][nt], 0, 0, 0);
      }
    }
    if (mi < 2) {
      u16* o = (mi == 0) ? qo : ko;
#pragma unroll
      for (int mt = 0; mt < 4; mt++) {
        int s = s0 + wm * 64 + mt * 16 + l16;
#pragma unroll
        for (int nt = 0; nt < 4; nt++) {
          int e0 = wn * 64 + nt * 16 + quad * 4;
          uint2 pk;
          pk.x = pk2bf(acc[mt][nt][0], acc[mt][nt][1]);
          pk.y = pk2bf(acc[mt][nt][2], acc[mt][nt][3]);
          *(uint2*)(o + ((size_t)bh * SEQ + s) * ESPL + e0) = pk;
        }
      }
    } else {
#pragma unroll
      for (int mt = 0; mt < 4; mt++)
#pragma unroll
        for (int nt = 0; nt < 4; nt++) {
          int e = wn * 64 + nt * 16 + l16;
          int sbase = s0 + wm * 64 + mt * 16 + quad * 4;
          uint2 pk;
          pk.x = pk2bf(acc[mt][nt][0], acc[mt][nt][1]);
          pk.y = pk2bf(acc[mt][nt][2], acc[mt][nt][3]);
          *(uint2*)(vto + ((size_t)bh * ESPL + e) * SEQ + sbase) = pk;
        }
    }
  }
}

// ------- MFMA flash attention v12: LDS-traffic-halved --------------------------
// 8 waves x 32 q-rows (g=2) -> 256-row block tile, grid 256 (1 blk/CU). Each
// kf/vf8 LDS read feeds 2 MFMAs (vs 1 in v11) -> QK^T/PV LDS reads per q-row
// halve. Epilogue: direct per-lane float4 RMW of mod (no Obuf, no barrier).
// LDS = 64 KB K/V dbuf + 32 KB P^T = 96 KB.
#define RESCALE_THR 8.f

__global__ __launch_bounds__(512, 2) void attn_mfma(const u16* __restrict__ q,
                                                    const u16* __restrict__ kk,
                                                    const u16* __restrict__ vt,
                                                    float* __restrict__ modp,
                                                    float* __restrict__ s1p,
                                                    float* __restrict__ s2p) {
  __shared__ __align__(16) char lds[98304];  // [Ks0|Vs0|Ks1|Vs1] + 32 KB P^T
  const int t = threadIdx.x;
  const int w = t >> 6, lane = t & 63, quad = lane >> 4, l16 = lane & 15;
  const int lin = blockIdx.x + gridDim.x * blockIdx.y;  // 0..255
  const int xcd = lin & 7, slot = lin >> 3;             // 32 slots per XCD
  const int qt = slot & 7;                              // 0..7 (256-row tiles)
  const int bh = xcd * 4 + (slot >> 3);                 // 4 bh per XCD
  const int b = bh >> 3, hh = bh & 7;
  const size_t qkbase = (size_t)bh * SEQ * ESPL;
  const int qrow0 = qt * 256 + w * 32;  // 32 q-rows per wave
  const u16* kg0 = kk + qkbase;
  const u16* vg0 = vt + qkbase;
  // per-wave P^T scratch: [g][q=l16][k 0..63] bf16, 16B-XOR-swizzled rows
  char* Pt = lds + 65536 + w * 4096;
  const int swz = (l16 & 7) << 4;

  short8 qf[2][4];
#pragma unroll
  for (int g = 0; g < 2; g++) {
    const u16* qrow = q + qkbase + (size_t)(qrow0 + g * 16 + l16) * ESPL + quad * 8;
#pragma unroll
    for (int kc = 0; kc < 4; kc++) qf[g][kc] = *(const short8*)(qrow + kc * 32);
  }

  float m_st[2] = {-1e30f, -1e30f}, l_st[2] = {0.f, 0.f};
  f32x4 oacc[2][8];
#pragma unroll
  for (int g = 0; g < 2; g++)
#pragma unroll
    for (int et = 0; et < 8; et++) oacc[g][et] = (f32x4){0.f, 0.f, 0.f, 0.f};

  auto stage = [&](int kt, int bi) {
    const u16* kg = kg0 + (size_t)kt * 64 * ESPL;
    const u16* vg = vg0 + (size_t)kt * 64;
    u16* Ksb = (u16*)(lds + bi * 32768);
    u16* Vsb = (u16*)(lds + bi * 32768 + 16384);
#pragma unroll
    for (int i = 0; i < 2; i++) {
      int pbase = w * 128 + i * 64;
      int p = pbase + lane;
      int r = p >> 4, c8 = (p & 15) ^ (r & 15);
      gl2lds16(kg + r * ESPL + c8 * 8, Ksb + pbase * 8);
      int e = p >> 3, v8 = (p & 7) ^ (e & 7);
      gl2lds16(vg + (size_t)e * SEQ + v8 * 8, Vsb + pbase * 8);
    }
  };

  stage(0, 0);
  __syncthreads();

  for (int kt = 0; kt < SEQ / 64; kt++) {
    if (kt + 1 < SEQ / 64) stage(kt + 1, (kt + 1) & 1);
    const u16* Ks = (const u16*)(lds + (kt & 1) * 32768);
    const u16* Vs = (const u16*)(lds + (kt & 1) * 32768 + 16384);
    f32x4 sacc[4][2];
#pragma unroll
    for (int mt = 0; mt < 4; mt++)
#pragma unroll
      for (int g = 0; g < 2; g++) sacc[mt][g] = (f32x4){0.f, 0.f, 0.f, 0.f};
    __builtin_amdgcn_s_setprio(1);
#pragma unroll
    for (int mt = 0; mt < 4; mt++) {
#pragma unroll
      for (int kc = 0; kc < 4; kc++) {
        short8 kf = *(const short8*)(Ks + (mt * 16 + l16) * 128 + (((kc * 4 + quad) ^ l16) << 3));
        sacc[mt][0] = __builtin_amdgcn_mfma_f32_16x16x32_bf16(kf, qf[0][kc], sacc[mt][0], 0, 0, 0);
        sacc[mt][1] = __builtin_amdgcn_mfma_f32_16x16x32_bf16(kf, qf[1][kc], sacc[mt][1], 0, 0, 0);
      }
    }
    __builtin_amdgcn_s_setprio(0);
    float alpha[2];
    bool updf[2];
#pragma unroll
    for (int g = 0; g < 2; g++) {
      const f32x4 a = sacc[0][g], b2 = sacc[1][g], c2 = sacc[2][g], d2 = sacc[3][g];
      float t0 = fmaxf(fmaxf(a[0], a[1]), a[2]);
      float t1 = fmaxf(fmaxf(a[3], b2[0]), b2[1]);
      float t2 = fmaxf(fmaxf(b2[2], b2[3]), c2[0]);
      float t3 = fmaxf(fmaxf(c2[1], c2[2]), c2[3]);
      float t4 = fmaxf(fmaxf(d2[0], d2[1]), d2[2]);
      float mloc = fmaxf(fmaxf(fmaxf(t0, t1), t2), fmaxf(fmaxf(t3, t4), d2[3]));
      mloc = fmaxf(mloc, __shfl_xor(mloc, 16));
      mloc = fmaxf(mloc, __shfl_xor(mloc, 32));
      // defer-max (T13)
      updf[g] = !__all(mloc - m_st[g] <= RESCALE_THR);
      if (updf[g]) {
        float mnew = fmaxf(m_st[g], mloc);
        alpha[g] = fexp2((m_st[g] - mnew) * L2E);
        m_st[g] = mnew;
      } else {
        alpha[g] = 1.f;
      }
      const float mkn = -m_st[g] * L2E;  // fold max-subtract into the exp2 fma
      float sum = 0.f;
#pragma unroll
      for (int mt = 0; mt < 4; mt++) {
        float p0 = fexp2(fmaf(sacc[mt][g][0], L2E, mkn));
        float p1 = fexp2(fmaf(sacc[mt][g][1], L2E, mkn));
        float p2 = fexp2(fmaf(sacc[mt][g][2], L2E, mkn));
        float p3 = fexp2(fmaf(sacc[mt][g][3], L2E, mkn));
        sum += (p0 + p1) + (p2 + p3);
        uint2 pkv = make_uint2(pk2bf(p0, p1), pk2bf(p2, p3));
        // P^T[q=l16][k = mt*16 + quad*4 + 0..3] (bf16), 16B-granular XOR swizzle
        *(uint2*)(Pt + g * 2048 + l16 * 128 + ((mt * 32 + quad * 8) ^ swz)) = pkv;
      }
      sum += __shfl_xor(sum, 16);
      sum += __shfl_xor(sum, 32);
      l_st[g] = l_st[g] * alpha[g] + sum;
    }
    if (updf[0]) {  // wave-uniform branch (from __all)
#pragma unroll
      for (int et = 0; et < 8; et++)
#pragma unroll
        for (int r = 0; r < 4; r++) oacc[0][et][r] *= alpha[0];
    }
    if (updf[1]) {
#pragma unroll
      for (int et = 0; et < 8; et++)
#pragma unroll
        for (int r = 0; r < 4; r++) oacc[1][et][r] *= alpha[1];
    }
    // B-fragments for 16x16x32 PV: one contiguous b128 from own P^T row
    short8 pb[2][2];
#pragma unroll
    for (int g = 0; g < 2; g++)
#pragma unroll
      for (int mtp = 0; mtp < 2; mtp++)
        pb[g][mtp] = *(const short8*)(Pt + g * 2048 + l16 * 128 + ((mtp * 64 + quad * 16) ^ swz));
    __builtin_amdgcn_s_setprio(1);
#pragma unroll
    for (int et = 0; et < 8; et++) {
#pragma unroll
      for (int mtp = 0; mtp < 2; mtp++) {
        short8 vf8 = *(const short8*)(Vs + (size_t)(et * 16 + l16) * 64 +
                                      (((mtp * 4 + quad) ^ (l16 & 7)) << 3));
        oacc[0][et] = __builtin_amdgcn_mfma_f32_16x16x32_bf16(vf8, pb[0][mtp], oacc[0][et], 0, 0, 0);
        oacc[1][et] = __builtin_amdgcn_mfma_f32_16x16x32_bf16(vf8, pb[1][mtp], oacc[1][et], 0, 0, 0);
      }
    }
    __builtin_amdgcn_s_setprio(0);
    __syncthreads();  // drains DMA + all waves done reading this buffer
  }

  // direct-RMW epilogue: lane holds q = qrow0+g*16+l16, e = et*16+quad*4+0..3
  // (same mapping the old Obuf write used); no LDS, no barrier.
#pragma unroll
  for (int g = 0; g < 2; g++) {
    float linv = 1.f / l_st[g];
    int qglob = qrow0 + g * 16 + l16;
    float* mp = modp + ((size_t)(b * SEQ + qglob)) * DIMN + hh * ESPL;
    float s1 = 0.f, s2 = 0.f;
#pragma unroll
    for (int et = 0; et < 8; et++) {
      int e0 = et * 16 + quad * 4;
      f32x4 ov = oacc[g][et];
      float4 mv = *(const float4*)(mp + e0);
      mv.x += ov[0] * linv;
      mv.y += ov[1] * linv;
      mv.z += ov[2] * linv;
      mv.w += ov[3] * linv;
      *(float4*)(mp + e0) = mv;
      s1 += (mv.x + mv.y) + (mv.z + mv.w);
      s2 += (mv.x * mv.x + mv.y * mv.y) + (mv.z * mv.z + mv.w * mv.w);
    }
    // reduce across quads (same q row, different e quarters)
    s1 += __shfl_xor(s1, 16);
    s1 += __shfl_xor(s1, 32);
    s2 += __shfl_xor(s2, 16);
    s2 += __shfl_xor(s2, 32);
    if (quad == 0) {
      atomicAdd(s1p + b * SEQ + qglob, s1);
      atomicAdd(s2p + b * SEQ + qglob, s2);
    }
  }
}

extern "C" void kernel_launch(void* const* d_in, const int* in_sizes, int n_in, void* d_out,
                              int out_size, void* d_ws, size_t ws_size, hipStream_t stream) {
  (void)in_sizes;
  (void)n_in;
  (void)out_size;
  (void)ws_size;
  const float* x = (const float*)d_in[0];
  const float* W_in = (const float*)d_in[1];
  const float* gamma = (const float*)d_in[2];
  const float* beta = (const float*)d_in[3];
  const float* Wq = (const float*)d_in[4];
  const float* Wk = (const float*)d_in[5];
  const float* Wv = (const float*)d_in[6];
  const float* Wf = (const float*)d_in[7];
  const float* bf = (const float*)d_in[8];
  float* out = (float*)d_out;

  char* ws = (char*)d_ws;
  const size_t MB = 1024ull * 1024;
  float* mod = (float*)ws;               // 32 MB fp32 [8192,1024]
  u16* qb = (u16*)(ws + 32 * MB);        // 16 MB bf16 [B,H,S,E]
  u16* kb = (u16*)(ws + 48 * MB);        // 16 MB bf16 [B,H,S,E]
  u16* vtb = (u16*)(ws + 64 * MB);       // 16 MB bf16 [B,H,E,S]
  float* sums = (float*)(ws + 80 * MB);  // 4 x 32 KB: s1a,s2a,s1b,s2b
  float* s1a = sums;
  float* s2a = s1a + NROWS;
  float* s1b = s2a + NROWS;
  float* s2b = s1b + NROWS;
  u16* wqt = (u16*)(ws + 80 * MB + 4 * NROWS * sizeof(float));
  u16* wkt = wqt + NHEAD * ESPL * ESPL;
  u16* wvt = wkt + NHEAD * ESPL * ESPL;
  u16* wt2 = wvt + NHEAD * ESPL * ESPL;  // 2 MB Wf^T bf16
  // overlays (lifetimes disjoint, stream-serial):
  u16* wt1 = qb;   // W_in^T bf16: prep -> gemm1; qb written by qkv after gemm1
  u16* xb = kb;    // x bf16: prep -> gemm1; kb written by qkv after gemm1
  u16* modb = qb;  // LN2(mod) bf16: ln_apply -> gemm2; qb dead after attn

  hipMemsetAsync(sums, 0, 4 * NROWS * sizeof(float), stream);
  prep_fused<<<NROWS + 512 + 96, 256, 0, stream>>>(x, xb, W_in, wt1, Wf, wt2, Wq, Wk, Wv, wqt,
                                                   wkt, wvt);

  dim3 gg(DIMN / 128, NROWS / 128);  // (8, 64)
  gemm_bf16<0><<<gg, 256, 0, stream>>>(xb, wt1, nullptr, nullptr, s1a, s2a, mod);
  qkv_mfma<<<dim3(SEQ / 128, NB * NHEAD), 256, 0, stream>>>(mod, wqt, wkt, wvt, gamma, beta,
                                                            s1a, s2a, qb, kb, vtb);
  attn_mfma<<<dim3(SEQ / 256, NB * NHEAD), 512, 0, stream>>>(qb, kb, vtb, mod, s1b, s2b);
  ln_apply<<<NROWS * DIMN / 1024, 256, 0, stream>>>(mod, gamma, beta, s1b, s2b, modb);
  gemm_bf16<1><<<gg, 256, 0, stream>>>(modb, wt2, mod, bf, nullptr, nullptr, out);
}

// Round 10
// 269.983 us; speedup vs baseline: 1.0991x; 1.0554x over previous
//
#include <hip/hip_runtime.h>
#include <hip/hip_bf16.h>

#define DIMN 1024
#define NHEAD 8
#define ESPL 128
#define NB 4
#define SEQ 2048
#define NROWS (NB * SEQ)
#define LNEPS 1e-6f
#define L2E 1.442695041f

typedef unsigned short u16;
typedef unsigned int u32;
typedef __attribute__((ext_vector_type(8))) short short8;
typedef __attribute__((ext_vector_type(4))) short s16x4;
typedef __attribute__((ext_vector_type(4))) float f32x4;

__device__ __forceinline__ u16 f2bf(float f) {
  u32 u = __float_as_uint(f);
  u += 0x7FFFu + ((u >> 16) & 1u);  // round-to-nearest-even
  return (u16)(u >> 16);
}

// single-instruction pack of 2 f32 -> 2 bf16 (RNE), T12 (learn_hip m214v22)
__device__ __forceinline__ u32 pk2bf(float a, float b) {
  u32 r;
  asm("v_cvt_pk_bf16_f32 %0, %1, %2" : "=v"(r) : "v"(a), "v"(b));
  return r;
}

__device__ __forceinline__ uint2 pack4bf(float4 v) {
  uint2 r;
  r.x = pk2bf(v.x, v.y);
  r.y = pk2bf(v.z, v.w);
  return r;
}

// native 2^x (v_exp_f32); gfx9 VALU deps are HW-interlocked so inline asm is safe
__device__ __forceinline__ float fexp2(float x) {
  float r;
  asm("v_exp_f32 %0, %1" : "=v"(r) : "v"(x));
  return r;
}

__device__ __forceinline__ float eluf(float x) { return x > 0.f ? x : expm1f(x); }

// async global->LDS DMA, 16 B per lane; lds dest = wave-uniform base + lane*16
__device__ __forceinline__ void gl2lds16(const u16* g, u16* l) {
  __builtin_amdgcn_global_load_lds((const __attribute__((address_space(1))) u32*)g,
                                   (__attribute__((address_space(3))) u32*)l, 16, 0, 0);
}

// ------- weight transpose + fp32->bf16: dst[n*K+k] = bf16(src[k*N+n]) -------
__device__ __forceinline__ void wtrans_body(u16 (*tl)[68], const float* __restrict__ src,
                                            u16* __restrict__ dst, int K, int N, int n0,
                                            int k0) {
  const int t = threadIdx.x;
  const int r = t >> 2;
#pragma unroll
  for (int j = 0; j < 4; j++) {
    int f = (t & 3) + j * 4;
    float4 v = *(const float4*)(src + (size_t)(k0 + r) * N + n0 + f * 4);
    *(uint2*)&tl[r][f * 4] = pack4bf(v);
  }
  __syncthreads();
#pragma unroll
  for (int j = 0; j < 4; j++) {
    int f = (t & 3) + j * 4;
    ushort4 o;
    o.x = tl[f * 4 + 0][r];
    o.y = tl[f * 4 + 1][r];
    o.z = tl[f * 4 + 2][r];
    o.w = tl[f * 4 + 3][r];
    *(ushort4*)(dst + (size_t)(n0 + r) * K + k0 + f * 4) = o;
  }
}

// ------- fused prep: x->bf16 convert + all weight transposes in ONE launch -----
__global__ __launch_bounds__(256) void prep_fused(
    const float* __restrict__ x, u16* __restrict__ xb, const float* __restrict__ W_in,
    u16* __restrict__ wt1, const float* __restrict__ Wf, u16* __restrict__ wt2,
    const float* __restrict__ Wq, const float* __restrict__ Wk, const float* __restrict__ Wv,
    u16* __restrict__ dq, u16* __restrict__ dk, u16* __restrict__ dv) {
  __shared__ u16 tl[64][68];
  const int bid = blockIdx.x;
  if (bid < NROWS) {
    int base = (bid * 256 + threadIdx.x) * 4;
    *(uint2*)(xb + base) = pack4bf(*(const float4*)(x + base));
  } else if (bid < NROWS + 512) {
    int z = bid - NROWS;
    const float* s = (z & 256) ? Wf : W_in;
    u16* d = (z & 256) ? wt2 : wt1;
    z &= 255;
    wtrans_body(tl, s, d, DIMN, DIMN, (z & 15) * 64, (z >> 4) * 64);
  } else {
    int z = bid - NROWS - 512;  // 0..95
    int xy = z & 3, zz = z >> 2;
    int mi = zz >> 3, hh = zz & 7;
    const float* s = (mi == 0) ? Wq : (mi == 1) ? Wk : Wv;
    u16* d = (mi == 0) ? dq : (mi == 1) ? dk : dv;
    s += (size_t)hh * ESPL * ESPL;
    d += (size_t)hh * ESPL * ESPL;
    wtrans_body(tl, s, d, ESPL, ESPL, (xy & 1) * 64, (xy >> 1) * 64);
  }
}

// ------- pure-bf16 MFMA GEMM: async-DMA double-buffered, 128x128 tile, BK=64 -------
// MODE 0: A bf16 via DMA; C fp32 + row sum/sumsq atomics.
// MODE 1: A = LN(Af fp32; s1p/s2p row sums) * gamma + beta, bf16-packed during
//         reg-staging (T14 split: loads issued before compute, LN+ds_write after);
//         byte layout identical to the DMA path. C = resid + elu(acc + bias).
template <int MODE>
__global__ __launch_bounds__(256, 2) void gemm_bf16(
    const u16* __restrict__ A, const u16* __restrict__ Bt, const float* __restrict__ Af,
    const float* __restrict__ resid, const float* __restrict__ bias,
    const float* __restrict__ gamma, const float* __restrict__ beta,
    float* __restrict__ s1p, float* __restrict__ s2p, float* __restrict__ C) {
  __shared__ __align__(16) char lds[65536];  // [As0|Bs0|As1|Bs1] 16 KB each
  const int t = threadIdx.x;
  const int w = t >> 6, lane = t & 63, quad = lane >> 4, l16 = lane & 15;
  const int wm = w & 1, wn = w >> 1;
  const int lin = blockIdx.x + gridDim.x * blockIdx.y;  // 0..511
  const int xcd = lin & 7, slot = lin >> 3;             // 64 slots per XCD
  const int m0 = (xcd * 8 + (slot >> 3)) * 128;
  const int n0 = (slot & 7) * 128;

  auto stageB = [&](int koff, int bi) {
    const u16* bg = Bt + (size_t)n0 * DIMN + koff;
    u16* Bs = (u16*)(lds + bi * 32768 + 16384);
#pragma unroll
    for (int i = 0; i < 4; i++) {
      int pbase = (w * 4 + i) * 64;
      int p = pbase + lane;
      int r = p >> 3, c8 = (p & 7) ^ (r & 7);
      gl2lds16(bg + (size_t)r * DIMN + c8 * 8, Bs + pbase * 8);
    }
  };
  auto stageA_dma = [&](int koff, int bi) {
    const u16* ag = A + (size_t)m0 * DIMN + koff;
    u16* As = (u16*)(lds + bi * 32768);
#pragma unroll
    for (int i = 0; i < 4; i++) {
      int pbase = (w * 4 + i) * 64;
      int p = pbase + lane;
      int r = p >> 3, c8 = (p & 7) ^ (r & 7);
      gl2lds16(ag + (size_t)r * DIMN + c8 * 8, As + pbase * 8);
    }
  };

  // MODE 1: LN-fused reg-staging state (4 p-slots per thread, rows fixed)
  float4 av0[4], av1[4];
  float mu4[4], rs4[4];
  if (MODE == 1) {
#pragma unroll
    for (int i = 0; i < 4; i++) {
      int r = (t >> 3) + 32 * i;
      float s1 = s1p[m0 + r], s2 = s2p[m0 + r];
      float mu = s1 * (1.f / DIMN);
      mu4[i] = mu;
      rs4[i] = rsqrtf(fmaxf(s2 * (1.f / DIMN) - mu * mu, 0.f) + LNEPS);
    }
  }
  auto ldA = [&](int koff) {  // issue loads early (hide under compute)
#pragma unroll
    for (int i = 0; i < 4; i++) {
      int p = t + i * 256;
      int r = p >> 3, c8 = (p & 7) ^ (r & 7);
      const float* src = Af + (size_t)(m0 + r) * DIMN + koff + c8 * 8;
      av0[i] = *(const float4*)(src);
      av1[i] = *(const float4*)(src + 4);
    }
  };
  auto wrA = [&](int koff, int bi) {  // LN + pack + ds_write (late)
    u16* As = (u16*)(lds + bi * 32768);
#pragma unroll
    for (int i = 0; i < 4; i++) {
      int p = t + i * 256;
      int r = p >> 3, c8 = (p & 7) ^ (r & 7);
      int col = koff + c8 * 8;
      float4 g0 = *(const float4*)(gamma + col);
      float4 g1 = *(const float4*)(gamma + col + 4);
      float4 b0 = *(const float4*)(beta + col);
      float4 b1 = *(const float4*)(beta + col + 4);
      float4 v0 = av0[i], v1 = av1[i];
      v0.x = (v0.x - mu4[i]) * rs4[i] * g0.x + b0.x;
      v0.y = (v0.y - mu4[i]) * rs4[i] * g0.y + b0.y;
      v0.z = (v0.z - mu4[i]) * rs4[i] * g0.z + b0.z;
      v0.w = (v0.w - mu4[i]) * rs4[i] * g0.w + b0.w;
      v1.x = (v1.x - mu4[i]) * rs4[i] * g1.x + b1.x;
      v1.y = (v1.y - mu4[i]) * rs4[i] * g1.y + b1.y;
      v1.z = (v1.z - mu4[i]) * rs4[i] * g1.z + b1.z;
      v1.w = (v1.w - mu4[i]) * rs4[i] * g1.w + b1.w;
      uint4 pk;
      pk.x = pk2bf(v0.x, v0.y);
      pk.y = pk2bf(v0.z, v0.w);
      pk.z = pk2bf(v1.x, v1.y);
      pk.w = pk2bf(v1.z, v1.w);
      *(uint4*)(As + (size_t)p * 8) = pk;  // 16B at As + p*16 (== DMA layout)
    }
  };

  f32x4 acc[4][4];
#pragma unroll
  for (int mt = 0; mt < 4; mt++)
#pragma unroll
    for (int nt = 0; nt < 4; nt++) acc[mt][nt] = (f32x4){0.f, 0.f, 0.f, 0.f};

  if (MODE == 1) {
    ldA(0);
    stageB(0, 0);
    wrA(0, 0);
  } else {
    stageA_dma(0, 0);
    stageB(0, 0);
  }
  __syncthreads();
  for (int kt = 0; kt < DIMN / 64; kt++) {
    if (kt + 1 < DIMN / 64) {
      if (MODE == 1)
        ldA((kt + 1) * 64);
      else
        stageA_dma((kt + 1) * 64, (kt + 1) & 1);
      stageB((kt + 1) * 64, (kt + 1) & 1);
    }
    const u16* As = (const u16*)(lds + (kt & 1) * 32768);
    const u16* Bs = (const u16*)(lds + (kt & 1) * 32768 + 16384);
#pragma unroll
    for (int ks = 0; ks < 2; ks++) {
      short8 af[4], bfr[4];
#pragma unroll
      for (int mt = 0; mt < 4; mt++) {
        int row = wm * 64 + mt * 16 + l16;
        int pc = (ks * 4 + quad) ^ (row & 7);
        af[mt] = *(const short8*)(As + row * 64 + pc * 8);
      }
#pragma unroll
      for (int nt = 0; nt < 4; nt++) {
        int row = wn * 64 + nt * 16 + l16;
        int pc = (ks * 4 + quad) ^ (row & 7);
        bfr[nt] = *(const short8*)(Bs + row * 64 + pc * 8);
      }
#pragma unroll
      for (int mt = 0; mt < 4; mt++)
#pragma unroll
        for (int nt = 0; nt < 4; nt++)
          acc[mt][nt] = __builtin_amdgcn_mfma_f32_16x16x32_bf16(bfr[nt], af[mt], acc[mt][nt], 0, 0, 0);
    }
    if (MODE == 1 && kt + 1 < DIMN / 64) wrA((kt + 1) * 64, (kt + 1) & 1);
    __syncthreads();
  }
  // epilogue: row m = ..+l16 (quad-invariant); cols n = ..+quad*4+r
#pragma unroll
  for (int mt = 0; mt < 4; mt++) {
    int row = m0 + wm * 64 + mt * 16 + l16;
    float s1 = 0.f, s2 = 0.f;
#pragma unroll
    for (int nt = 0; nt < 4; nt++) {
      int col = n0 + wn * 64 + nt * 16 + quad * 4;
      size_t off = (size_t)row * DIMN + col;
      f32x4 v = acc[mt][nt];
      if (MODE == 0) {
        *(f32x4*)(C + off) = v;
        s1 += (v[0] + v[1]) + (v[2] + v[3]);
        s2 += (v[0] * v[0] + v[1] * v[1]) + (v[2] * v[2] + v[3] * v[3]);
      } else {
        float4 rv = *(const float4*)(resid + off);
        float4 bv = *(const float4*)(bias + col);
        float4 o;
        o.x = rv.x + eluf(v[0] + bv.x);
        o.y = rv.y + eluf(v[1] + bv.y);
        o.z = rv.z + eluf(v[2] + bv.z);
        o.w = rv.w + eluf(v[3] + bv.w);
        *(float4*)(C + off) = o;
      }
    }
    if (MODE == 0) {
      s1 += __shfl_xor(s1, 16);
      s1 += __shfl_xor(s1, 32);
      s2 += __shfl_xor(s2, 16);
      s2 += __shfl_xor(s2, 32);
      if (quad == 0) {
        atomicAdd(s1p + row, s1);
        atomicAdd(s2p + row, s2);
      }
    }
  }
}

// ------- QKV: per (b,h), 128 s-rows x 128 e, K=128; LN1 fused in A-staging -------
// B (weights) staged via global_load_lds with the attn-K XOR swizzle
// (c8=(p&15)^(r&15)); reads use chunk=(k4*4+quad)^l16 — byte-identical mapping.
#define QP 136

__global__ __launch_bounds__(256) void qkv_mfma(
    const float* __restrict__ modp, const u16* __restrict__ wqt, const u16* __restrict__ wkt,
    const u16* __restrict__ wvt, const float* __restrict__ gamma, const float* __restrict__ beta,
    const float* __restrict__ s1p, const float* __restrict__ s2p, u16* __restrict__ qo,
    u16* __restrict__ ko, u16* __restrict__ vto) {
  __shared__ u16 Asl[128 * QP];
  __shared__ __align__(16) u16 Bsl[128 * 128];
  const int t = threadIdx.x;
  const int w = t >> 6, lane = t & 63, quad = lane >> 4, l16 = lane & 15;
  const int wm = w & 1, wn = w >> 1;
  const int lin = blockIdx.x + gridDim.x * blockIdx.y;  // 0..511
  const int xcd = lin & 7, slot = lin >> 3;
  const int s0 = (slot >> 2) * 128;
  const int bh = (slot & 3) * 8 + xcd;  // hh == xcd
  const int b = bh >> 3, hh = bh & 7;
  const int sr8 = t >> 3, sf8 = t & 7;
#pragma unroll
  for (int p = 0; p < 4; p++) {
    int r = sr8 + 32 * p;
    int rowg = b * SEQ + s0 + r;
    float s1 = s1p[rowg], s2 = s2p[rowg];
    float mu = s1 * (1.f / DIMN);
    float rsd = rsqrtf(fmaxf(s2 * (1.f / DIMN) - mu * mu, 0.f) + LNEPS);
    const float* ap = modp + (size_t)rowg * DIMN + hh * ESPL;
#pragma unroll
    for (int j = 0; j < 4; j++) {
      int f = sf8 + j * 8;
      float4 v = *(const float4*)(ap + f * 4);
      float4 g = *(const float4*)(gamma + hh * ESPL + f * 4);
      float4 bb = *(const float4*)(beta + hh * ESPL + f * 4);
      v.x = (v.x - mu) * rsd * g.x + bb.x;
      v.y = (v.y - mu) * rsd * g.y + bb.y;
      v.z = (v.z - mu) * rsd * g.z + bb.z;
      v.w = (v.w - mu) * rsd * g.w + bb.w;
      *(uint2*)(Asl + r * QP + f * 4) = pack4bf(v);
    }
  }
  __syncthreads();
  short8 afr[4][4];
#pragma unroll
  for (int k4 = 0; k4 < 4; k4++)
#pragma unroll
    for (int mt = 0; mt < 4; mt++)
      afr[k4][mt] = *(const short8*)(Asl + (wm * 64 + mt * 16 + l16) * QP + k4 * 32 + quad * 8);

  const u16* Ws[3] = {wqt, wkt, wvt};
  for (int mi = 0; mi < 3; mi++) {
    __syncthreads();
    const u16* wsrc = Ws[mi] + ((size_t)hh << 14);
#pragma unroll
    for (int i = 0; i < 8; i++) {
      int pbase = w * 64 + i * 256;
      int p = pbase + lane;
      int r = p >> 4, c8 = (p & 15) ^ (r & 15);
      gl2lds16(wsrc + r * ESPL + c8 * 8, Bsl + pbase * 8);
    }
    __syncthreads();
    f32x4 acc[4][4];
#pragma unroll
    for (int mt = 0; mt < 4; mt++)
#pragma unroll
      for (int nt = 0; nt < 4; nt++) acc[mt][nt] = (f32x4){0.f, 0.f, 0.f, 0.f};
#pragma unroll
    for (int k4 = 0; k4 < 4; k4++) {
      short8 bfr[4];
#pragma unroll
      for (int nt = 0; nt < 4; nt++) {
        int row = wn * 64 + nt * 16 + l16;
        bfr[nt] = *(const short8*)(Bsl + row * 128 + (((k4 * 4 + quad) ^ l16) << 3));
      }
      if (mi < 2) {
#pragma unroll
        for (int mt = 0; mt < 4; mt++)
#pragma unroll
          for (int nt = 0; nt < 4; nt++)
            acc[mt][nt] = __builtin_amdgcn_mfma_f32_16x16x32_bf16(bfr[nt], afr[k4][mt], acc[mt][nt], 0, 0, 0);
      } else {
#pragma unroll
        for (int mt = 0; mt < 4; mt++)
#pragma unroll
          for (int nt = 0; nt < 4; nt++)
            acc[mt][nt] = __builtin_amdgcn_mfma_f32_16x16x32_bf16(afr[k4][mt], bfr[nt], acc[mt][nt], 0, 0, 0);
      }
    }
    if (mi < 2) {
      u16* o = (mi == 0) ? qo : ko;
#pragma unroll
      for (int mt = 0; mt < 4; mt++) {
        int s = s0 + wm * 64 + mt * 16 + l16;
#pragma unroll
        for (int nt = 0; nt < 4; nt++) {
          int e0 = wn * 64 + nt * 16 + quad * 4;
          uint2 pk;
          pk.x = pk2bf(acc[mt][nt][0], acc[mt][nt][1]);
          pk.y = pk2bf(acc[mt][nt][2], acc[mt][nt][3]);
          *(uint2*)(o + ((size_t)bh * SEQ + s) * ESPL + e0) = pk;
        }
      }
    } else {
#pragma unroll
      for (int mt = 0; mt < 4; mt++)
#pragma unroll
        for (int nt = 0; nt < 4; nt++) {
          int e = wn * 64 + nt * 16 + l16;
          int sbase = s0 + wm * 64 + mt * 16 + quad * 4;
          uint2 pk;
          pk.x = pk2bf(acc[mt][nt][0], acc[mt][nt][1]);
          pk.y = pk2bf(acc[mt][nt][2], acc[mt][nt][3]);
          *(uint2*)(vto + ((size_t)bh * ESPL + e) * SEQ + sbase) = pk;
        }
    }
  }
}

// ------- MFMA flash attention v12 (verified): LDS-traffic-halved ---------------
// 8 waves x 32 q-rows (g=2) -> 256-row block tile, grid 256. Direct-RMW epilogue.
#define RESCALE_THR 8.f

__global__ __launch_bounds__(512, 2) void attn_mfma(const u16* __restrict__ q,
                                                    const u16* __restrict__ kk,
                                                    const u16* __restrict__ vt,
                                                    float* __restrict__ modp,
                                                    float* __restrict__ s1p,
                                                    float* __restrict__ s2p) {
  __shared__ __align__(16) char lds[98304];  // [Ks0|Vs0|Ks1|Vs1] + 32 KB P^T
  const int t = threadIdx.x;
  const int w = t >> 6, lane = t & 63, quad = lane >> 4, l16 = lane & 15;
  const int lin = blockIdx.x + gridDim.x * blockIdx.y;  // 0..255
  const int xcd = lin & 7, slot = lin >> 3;             // 32 slots per XCD
  const int qt = slot & 7;                              // 0..7 (256-row tiles)
  const int bh = xcd * 4 + (slot >> 3);                 // 4 bh per XCD
  const int b = bh >> 3, hh = bh & 7;
  const size_t qkbase = (size_t)bh * SEQ * ESPL;
  const int qrow0 = qt * 256 + w * 32;  // 32 q-rows per wave
  const u16* kg0 = kk + qkbase;
  const u16* vg0 = vt + qkbase;
  // per-wave P^T scratch: [g][q=l16][k 0..63] bf16, 16B-XOR-swizzled rows
  char* Pt = lds + 65536 + w * 4096;
  const int swz = (l16 & 7) << 4;

  short8 qf[2][4];
#pragma unroll
  for (int g = 0; g < 2; g++) {
    const u16* qrow = q + qkbase + (size_t)(qrow0 + g * 16 + l16) * ESPL + quad * 8;
#pragma unroll
    for (int kc = 0; kc < 4; kc++) qf[g][kc] = *(const short8*)(qrow + kc * 32);
  }

  float m_st[2] = {-1e30f, -1e30f}, l_st[2] = {0.f, 0.f};
  f32x4 oacc[2][8];
#pragma unroll
  for (int g = 0; g < 2; g++)
#pragma unroll
    for (int et = 0; et < 8; et++) oacc[g][et] = (f32x4){0.f, 0.f, 0.f, 0.f};

  auto stage = [&](int kt, int bi) {
    const u16* kg = kg0 + (size_t)kt * 64 * ESPL;
    const u16* vg = vg0 + (size_t)kt * 64;
    u16* Ksb = (u16*)(lds + bi * 32768);
    u16* Vsb = (u16*)(lds + bi * 32768 + 16384);
#pragma unroll
    for (int i = 0; i < 2; i++) {
      int pbase = w * 128 + i * 64;
      int p = pbase + lane;
      int r = p >> 4, c8 = (p & 15) ^ (r & 15);
      gl2lds16(kg + r * ESPL + c8 * 8, Ksb + pbase * 8);
      int e = p >> 3, v8 = (p & 7) ^ (e & 7);
      gl2lds16(vg + (size_t)e * SEQ + v8 * 8, Vsb + pbase * 8);
    }
  };

  stage(0, 0);
  __syncthreads();

  for (int kt = 0; kt < SEQ / 64; kt++) {
    if (kt + 1 < SEQ / 64) stage(kt + 1, (kt + 1) & 1);
    const u16* Ks = (const u16*)(lds + (kt & 1) * 32768);
    const u16* Vs = (const u16*)(lds + (kt & 1) * 32768 + 16384);
    f32x4 sacc[4][2];
#pragma unroll
    for (int mt = 0; mt < 4; mt++)
#pragma unroll
      for (int g = 0; g < 2; g++) sacc[mt][g] = (f32x4){0.f, 0.f, 0.f, 0.f};
    __builtin_amdgcn_s_setprio(1);
#pragma unroll
    for (int mt = 0; mt < 4; mt++) {
#pragma unroll
      for (int kc = 0; kc < 4; kc++) {
        short8 kf = *(const short8*)(Ks + (mt * 16 + l16) * 128 + (((kc * 4 + quad) ^ l16) << 3));
        sacc[mt][0] = __builtin_amdgcn_mfma_f32_16x16x32_bf16(kf, qf[0][kc], sacc[mt][0], 0, 0, 0);
        sacc[mt][1] = __builtin_amdgcn_mfma_f32_16x16x32_bf16(kf, qf[1][kc], sacc[mt][1], 0, 0, 0);
      }
    }
    __builtin_amdgcn_s_setprio(0);
    float alpha[2];
    bool updf[2];
#pragma unroll
    for (int g = 0; g < 2; g++) {
      const f32x4 a = sacc[0][g], b2 = sacc[1][g], c2 = sacc[2][g], d2 = sacc[3][g];
      float t0 = fmaxf(fmaxf(a[0], a[1]), a[2]);
      float t1 = fmaxf(fmaxf(a[3], b2[0]), b2[1]);
      float t2 = fmaxf(fmaxf(b2[2], b2[3]), c2[0]);
      float t3 = fmaxf(fmaxf(c2[1], c2[2]), c2[3]);
      float t4 = fmaxf(fmaxf(d2[0], d2[1]), d2[2]);
      float mloc = fmaxf(fmaxf(fmaxf(t0, t1), t2), fmaxf(fmaxf(t3, t4), d2[3]));
      mloc = fmaxf(mloc, __shfl_xor(mloc, 16));
      mloc = fmaxf(mloc, __shfl_xor(mloc, 32));
      // defer-max (T13)
      updf[g] = !__all(mloc - m_st[g] <= RESCALE_THR);
      if (updf[g]) {
        float mnew = fmaxf(m_st[g], mloc);
        alpha[g] = fexp2((m_st[g] - mnew) * L2E);
        m_st[g] = mnew;
      } else {
        alpha[g] = 1.f;
      }
      const float mkn = -m_st[g] * L2E;  // fold max-subtract into the exp2 fma
      float sum = 0.f;
#pragma unroll
      for (int mt = 0; mt < 4; mt++) {
        float p0 = fexp2(fmaf(sacc[mt][g][0], L2E, mkn));
        float p1 = fexp2(fmaf(sacc[mt][g][1], L2E, mkn));
        float p2 = fexp2(fmaf(sacc[mt][g][2], L2E, mkn));
        float p3 = fexp2(fmaf(sacc[mt][g][3], L2E, mkn));
        sum += (p0 + p1) + (p2 + p3);
        uint2 pkv = make_uint2(pk2bf(p0, p1), pk2bf(p2, p3));
        // P^T[q=l16][k = mt*16 + quad*4 + 0..3] (bf16), 16B-granular XOR swizzle
        *(uint2*)(Pt + g * 2048 + l16 * 128 + ((mt * 32 + quad * 8) ^ swz)) = pkv;
      }
      sum += __shfl_xor(sum, 16);
      sum += __shfl_xor(sum, 32);
      l_st[g] = l_st[g] * alpha[g] + sum;
    }
    if (updf[0]) {  // wave-uniform branch (from __all)
#pragma unroll
      for (int et = 0; et < 8; et++)
#pragma unroll
        for (int r = 0; r < 4; r++) oacc[0][et][r] *= alpha[0];
    }
    if (updf[1]) {
#pragma unroll
      for (int et = 0; et < 8; et++)
#pragma unroll
        for (int r = 0; r < 4; r++) oacc[1][et][r] *= alpha[1];
    }
    // B-fragments for 16x16x32 PV: one contiguous b128 from own P^T row
    short8 pb[2][2];
#pragma unroll
    for (int g = 0; g < 2; g++)
#pragma unroll
      for (int mtp = 0; mtp < 2; mtp++)
        pb[g][mtp] = *(const short8*)(Pt + g * 2048 + l16 * 128 + ((mtp * 64 + quad * 16) ^ swz));
    __builtin_amdgcn_s_setprio(1);
#pragma unroll
    for (int et = 0; et < 8; et++) {
#pragma unroll
      for (int mtp = 0; mtp < 2; mtp++) {
        short8 vf8 = *(const short8*)(Vs + (size_t)(et * 16 + l16) * 64 +
                                      (((mtp * 4 + quad) ^ (l16 & 7)) << 3));
        oacc[0][et] = __builtin_amdgcn_mfma_f32_16x16x32_bf16(vf8, pb[0][mtp], oacc[0][et], 0, 0, 0);
        oacc[1][et] = __builtin_amdgcn_mfma_f32_16x16x32_bf16(vf8, pb[1][mtp], oacc[1][et], 0, 0, 0);
      }
    }
    __builtin_amdgcn_s_setprio(0);
    __syncthreads();  // drains DMA + all waves done reading this buffer
  }

  // direct-RMW epilogue: lane holds q = qrow0+g*16+l16, e = et*16+quad*4+0..3
#pragma unroll
  for (int g = 0; g < 2; g++) {
    float linv = 1.f / l_st[g];
    int qglob = qrow0 + g * 16 + l16;
    float* mp = modp + ((size_t)(b * SEQ + qglob)) * DIMN + hh * ESPL;
    float s1 = 0.f, s2 = 0.f;
#pragma unroll
    for (int et = 0; et < 8; et++) {
      int e0 = et * 16 + quad * 4;
      f32x4 ov = oacc[g][et];
      float4 mv = *(const float4*)(mp + e0);
      mv.x += ov[0] * linv;
      mv.y += ov[1] * linv;
      mv.z += ov[2] * linv;
      mv.w += ov[3] * linv;
      *(float4*)(mp + e0) = mv;
      s1 += (mv.x + mv.y) + (mv.z + mv.w);
      s2 += (mv.x * mv.x + mv.y * mv.y) + (mv.z * mv.z + mv.w * mv.w);
    }
    // reduce across quads (same q row, different e quarters)
    s1 += __shfl_xor(s1, 16);
    s1 += __shfl_xor(s1, 32);
    s2 += __shfl_xor(s2, 16);
    s2 += __shfl_xor(s2, 32);
    if (quad == 0) {
      atomicAdd(s1p + b * SEQ + qglob, s1);
      atomicAdd(s2p + b * SEQ + qglob, s2);
    }
  }
}

extern "C" void kernel_launch(void* const* d_in, const int* in_sizes, int n_in, void* d_out,
                              int out_size, void* d_ws, size_t ws_size, hipStream_t stream) {
  (void)in_sizes;
  (void)n_in;
  (void)out_size;
  (void)ws_size;
  const float* x = (const float*)d_in[0];
  const float* W_in = (const float*)d_in[1];
  const float* gamma = (const float*)d_in[2];
  const float* beta = (const float*)d_in[3];
  const float* Wq = (const float*)d_in[4];
  const float* Wk = (const float*)d_in[5];
  const float* Wv = (const float*)d_in[6];
  const float* Wf = (const float*)d_in[7];
  const float* bf = (const float*)d_in[8];
  float* out = (float*)d_out;

  char* ws = (char*)d_ws;
  const size_t MB = 1024ull * 1024;
  float* mod = (float*)ws;               // 32 MB fp32 [8192,1024]
  u16* qb = (u16*)(ws + 32 * MB);        // 16 MB bf16 [B,H,S,E]
  u16* kb = (u16*)(ws + 48 * MB);        // 16 MB bf16 [B,H,S,E]
  u16* vtb = (u16*)(ws + 64 * MB);       // 16 MB bf16 [B,H,E,S]
  float* sums = (float*)(ws + 80 * MB);  // 4 x 32 KB: s1a,s2a,s1b,s2b
  float* s1a = sums;
  float* s2a = s1a + NROWS;
  float* s1b = s2a + NROWS;
  float* s2b = s1b + NROWS;
  u16* wqt = (u16*)(ws + 80 * MB + 4 * NROWS * sizeof(float));
  u16* wkt = wqt + NHEAD * ESPL * ESPL;
  u16* wvt = wkt + NHEAD * ESPL * ESPL;
  u16* wt2 = wvt + NHEAD * ESPL * ESPL;  // 2 MB Wf^T bf16
  // overlays (lifetimes disjoint, stream-serial):
  u16* wt1 = qb;  // W_in^T bf16: prep -> gemm1; qb written by qkv after gemm1
  u16* xb = kb;   // x bf16: prep -> gemm1; kb written by qkv after gemm1

  hipMemsetAsync(sums, 0, 4 * NROWS * sizeof(float), stream);
  prep_fused<<<NROWS + 512 + 96, 256, 0, stream>>>(x, xb, W_in, wt1, Wf, wt2, Wq, Wk, Wv, wqt,
                                                   wkt, wvt);

  dim3 gg(DIMN / 128, NROWS / 128);  // (8, 64)
  gemm_bf16<0><<<gg, 256, 0, stream>>>(xb, wt1, nullptr, nullptr, nullptr, nullptr, nullptr,
                                       s1a, s2a, mod);
  qkv_mfma<<<dim3(SEQ / 128, NB * NHEAD), 256, 0, stream>>>(mod, wqt, wkt, wvt, gamma, beta,
                                                            s1a, s2a, qb, kb, vtb);
  attn_mfma<<<dim3(SEQ / 256, NB * NHEAD), 512, 0, stream>>>(qb, kb, vtb, mod, s1b, s2b);
  // LN2 fused into gemm2's A-staging (ln_apply kernel eliminated)
  gemm_bf16<1><<<gg, 256, 0, stream>>>(nullptr, wt2, mod, mod, bf, gamma, beta, s1b, s2b, out);
}